// Round 13
// baseline (193.362 us; speedup 1.0000x reference)
//
#include <hip/hip_runtime.h>

typedef unsigned short u16;
typedef float f2 __attribute__((ext_vector_type(2)));

#define NQ 14
#define NSTATE (1 << NQ)   // 16384
#define DEPTH 8
#define TPB 1024

// ---------- host-side constants passed by value ----------
struct PassK {
  u16 pcol[10];    // PHYSICAL rep columns for t bits 0..9
  u16 sm[7];       // sign masks over t; slots 0..3 in-reg, 4..6 cross
  u16 widx[7];     // within-layer theta index per slot (0..13)
  u16 pxm[16];     // PHYSICAL xm (XOR combos of in-reg masks, mapped by Phi)
};

struct SimConsts {
  PassK pass[14];  // layers 1..7 x two 7-wire passes
  u16 zm[14];      // measurement sign masks over t (last-pass basis)
  u16 zfreq[14];   // 4-bit WHT frequency per wire (last-pass mask basis)
  u16 de[16];      // init-write address delta per e (Phi correction)
  u16 dcolw[4];    // init-write delta columns for t bits 6..9
};

// ---------- device ----------
__device__ __forceinline__ f2 cmulv(f2 a, f2 b) {
  f2 r;
  r.x = a.x * b.x - a.y * b.y;
  r.y = a.x * b.y + a.y * b.x;
  return r;
}

// Packed in-register butterfly: xn = x - t*y ; yn = y + t*x.
// Both results go to EARLY-CLOBBER fresh outputs so both instructions read
// only the original x,y (no stale-register aliasing hazard; the R12 version
// tied outputs and read a coalesced copy -> wrong results).
__device__ __forceinline__ void bfly_pk(f2& x, f2& y, f2 tp, f2 tn) {
  f2 xn, yn;
  asm("v_pk_fma_f32 %0, %4, %3, %2\n\t"   // xn = tn*y + x
      "v_pk_fma_f32 %1, %5, %2, %3"       // yn = tp*x + y
      : "=&v"(xn), "=&v"(yn)
      : "v"(x), "v"(y), "v"(tn), "v"(tp));
  x = xn; y = yn;
}

// Fused cross-wire butterfly: a += tg * partner(a), partner via DPP on src0.
// s_nop 1 covers the 2-wait-state VALU-write -> DPP-read hazard.
__device__ __forceinline__ void xfmac_l1(f2& v, float tg) {   // partner lane^1
  float x = v.x, y = v.y;
  asm volatile(
      "s_nop 1\n\t"
      "v_fmac_f32_dpp %0, %0, %2 quad_perm:[1,0,3,2] row_mask:0xf bank_mask:0xf\n\t"
      "v_fmac_f32_dpp %1, %1, %2 quad_perm:[1,0,3,2] row_mask:0xf bank_mask:0xf"
      : "+v"(x), "+v"(y) : "v"(tg));
  v.x = x; v.y = y;
}
__device__ __forceinline__ void xfmac_l2(f2& v, float tg) {   // partner lane^2
  float x = v.x, y = v.y;
  asm volatile(
      "s_nop 1\n\t"
      "v_fmac_f32_dpp %0, %0, %2 quad_perm:[2,3,0,1] row_mask:0xf bank_mask:0xf\n\t"
      "v_fmac_f32_dpp %1, %1, %2 quad_perm:[2,3,0,1] row_mask:0xf bank_mask:0xf"
      : "+v"(x), "+v"(y) : "v"(tg));
  v.x = x; v.y = y;
}
__device__ __forceinline__ void xfmac_l8(f2& v, float tg) {   // partner lane^8
  float x = v.x, y = v.y;
  asm volatile(
      "s_nop 1\n\t"
      "v_fmac_f32_dpp %0, %0, %2 row_ror:8 row_mask:0xf bank_mask:0xf\n\t"
      "v_fmac_f32_dpp %1, %1, %2 row_ror:8 row_mask:0xf bank_mask:0xf"
      : "+v"(x), "+v"(y) : "v"(tg));
  v.x = x; v.y = y;
}

// 7-wire RY pass in TANGENT form; 4 wires in-register (packed fma) + 3 via
// fused DPP-fmac (lane^1, lane^2, lane^8). Addresses PHYSICAL (Phi layout);
// signs from precomputed 10-bit t-masks. t bits 6..9 are wave-uniform ->
// their rep contribution goes through SALU.
template <bool USE_WS, bool WRITE>
__device__ __forceinline__ void ry7x(f2* st, const PassK& P, const float* th,
                                     const float2* tqd, int t, f2* a) {
  const unsigned wv = __builtin_amdgcn_readfirstlane(((unsigned)t) >> 6);
  unsigned rep = 0;
  #pragma unroll
  for (int j = 0; j < 4; ++j)
    rep ^= ((wv >> j) & 1u) ? (unsigned)P.pcol[6 + j] : 0u;   // SALU (uniform)
  #pragma unroll
  for (int b = 0; b < 6; ++b)
    rep ^= ((t >> b) & 1u) ? (unsigned)P.pcol[b] : 0u;        // VALU

  float tv[7];
  #pragma unroll
  for (int i = 0; i < 7; ++i) {
    if constexpr (USE_WS) {
      tv[i] = tqd[P.widx[i]].x;        // uniform -> s_load (tan(theta/2))
    } else {
      float ss, cc; __sincosf(0.5f * th[P.widx[i]], &ss, &cc);
      float ca = (fabsf(cc) < 1e-20f) ? copysignf(1e-20f, cc) : cc;
      tv[i] = ss / ca;
    }
  }
  float tg[7];
  #pragma unroll
  for (int i = 0; i < 4; ++i)
    tg[i] = (__popc((unsigned)P.sm[i] & (unsigned)t) & 1) ? -tv[i] : tv[i];
  #pragma unroll
  for (int i = 4; i < 7; ++i)
    tg[i] = (__popc((unsigned)P.sm[i] & (unsigned)t) & 1) ? tv[i] : -tv[i];

  const unsigned base = rep << 3;
  unsigned ad[16];
  #pragma unroll
  for (int e = 0; e < 16; ++e)
    ad[e] = base ^ (((unsigned)P.pxm[e]) << 3);   // pxm<<3 uniform (SGPR)

  #pragma unroll
  for (int e = 0; e < 16; ++e) a[e] = *(const f2*)((const char*)st + ad[e]);

  // cross slot 4: partner = lane^1
  #pragma unroll
  for (int e = 0; e < 16; ++e) xfmac_l1(a[e], tg[4]);
  // 4 in-register wires, packed butterflies
  #pragma unroll
  for (int i = 0; i < 4; ++i) {
    f2 tp, tn;
    tp.x = tg[i]; tp.y = tg[i];
    tn.x = -tg[i]; tn.y = -tg[i];
    #pragma unroll
    for (int e = 0; e < 16; ++e) {
      if (!(e & (1 << i))) bfly_pk(a[e], a[e | (1 << i)], tp, tn);
    }
  }
  // cross slot 5: partner = lane^2
  #pragma unroll
  for (int e = 0; e < 16; ++e) xfmac_l2(a[e], tg[5]);
  // cross slot 6: partner = lane^8
  #pragma unroll
  for (int e = 0; e < 16; ++e) xfmac_l8(a[e], tg[6]);

  if constexpr (WRITE) {
    #pragma unroll
    for (int e = 0; e < 16; ++e) *(f2*)((char*)st + ad[e]) = a[e];
  }
}

template <bool USE_WS>
__global__ __launch_bounds__(TPB, 1) void qsim_kernel(
    const float* __restrict__ inp, const float* __restrict__ theta,
    float* __restrict__ out, const float2* __restrict__ tt,
    const float2* __restrict__ tq, const float* __restrict__ s2p,
    const float4* __restrict__ albe, int use_albe, SimConsts C) {
  __shared__ f2 st[NSTATE];   // 128 KiB
  const int s = blockIdx.x;
  const int t = threadIdx.x;

  // ---- init: product state after RX(inp) then RY(theta layer 0) (full gates)
  f2 A[NQ], B[NQ];
  if constexpr (USE_WS) {
    if (use_albe) {
      #pragma unroll
      for (int w = 0; w < NQ; ++w) {
        float4 v = albe[s * NQ + w];       // uniform -> s_load_dwordx4
        A[w].x = v.x; A[w].y = v.y;
        B[w].x = v.z; B[w].y = v.w;
      }
    } else {
      #pragma unroll
      for (int w = 0; w < NQ; ++w) {
        float sx, cx; __sincosf(0.5f * inp[s * NQ + w], &sx, &cx);
        float2 tvv = tt[w];
        A[w].x = tvv.x * cx; A[w].y = tvv.y * sx;
        B[w].x = tvv.y * cx; B[w].y = -tvv.x * sx;
      }
    }
  } else {
    #pragma unroll
    for (int w = 0; w < NQ; ++w) {
      float sx, cx; __sincosf(0.5f * inp[s * NQ + w], &sx, &cx);
      float stt, ctt; __sincosf(0.5f * theta[w], &stt, &ctt);
      A[w].x = ctt * cx; A[w].y = stt * sx;
      B[w].x = stt * cx; B[w].y = -ctt * sx;
    }
  }

  f2 a[16];
  {
    f2 rhi; rhi.x = 1.f; rhi.y = 0.f;
    #pragma unroll
    for (int b = 0; b < 10; ++b) {         // p bit b <- t bit b, wire 13-b
      const int w = 13 - b;
      f2 f = ((t >> b) & 1) ? B[w] : A[w];
      rhi = cmulv(rhi, f);
    }
    a[0] = rhi;
    #pragma unroll
    for (int k = 0; k < 4; ++k) {          // e bit k <-> p bit 10+k <-> wire 3-k
      const int w = 3 - k;
      const int sz = 1 << k;
      #pragma unroll
      for (int j = 0; j < 8; ++j) {
        if (j < sz) {
          f2 v = a[j];
          a[j]      = cmulv(v, A[w]);
          a[j + sz] = cmulv(v, B[w]);
        }
      }
    }
    // Phi-corrected physical store addresses
    unsigned dw = 0;
    #pragma unroll
    for (int j = 0; j < 4; ++j)
      dw ^= ((t >> (6 + j)) & 1u) ? (unsigned)C.dcolw[j] : 0u;
    #pragma unroll
    for (int e = 0; e < 16; ++e)
      st[(((unsigned)e << 10) | (unsigned)t) ^ (unsigned)C.de[e] ^ dw] = a[e];
  }
  __syncthreads();

  // ---- layers 1..7, two 7-wire tangent passes each
  #pragma unroll 1
  for (int d = 1; d <= 6; ++d) {
    const float* th = theta + d * NQ;
    const float2* tqd = USE_WS ? (tq + d * NQ) : nullptr;
    ry7x<USE_WS, true>(st, C.pass[(d - 1) * 2 + 0], th, tqd, t, a);
    __syncthreads();
    ry7x<USE_WS, true>(st, C.pass[(d - 1) * 2 + 1], th, tqd, t, a);
    __syncthreads();
  }
  {
    const float* th = theta + 7 * NQ;
    const float2* tqd = USE_WS ? (tq + 7 * NQ) : nullptr;
    ry7x<USE_WS, true>(st, C.pass[12], th, tqd, t, a);
    __syncthreads();
    // last pass: keep results in registers, fuse measurement
    ry7x<USE_WS, false>(st, C.pass[13], th, tqd, t, a);
  }
  __syncthreads();   // all reads of the final pass done before st is reused

  // ---- measurement: per-thread |amp|^2, 4-bit WHT in mask basis
  float pv[16];
  #pragma unroll
  for (int e = 0; e < 16; ++e) pv[e] = a[e].x * a[e].x + a[e].y * a[e].y;
  #pragma unroll
  for (int s4 = 0; s4 < 4; ++s4) {
    const int step = 1 << s4;
    #pragma unroll
    for (int e = 0; e < 16; ++e) {
      if (!(e & step)) {
        float x = pv[e], y = pv[e | step];
        pv[e] = x + y; pv[e | step] = x - y;
      }
    }
  }
  float* stf = (float*)st;
  #pragma unroll
  for (int e = 0; e < 16; ++e) stf[(e << 10) | t] = pv[e];
  __syncthreads();

  float acc[NQ];
  #pragma unroll
  for (int w = 0; w < NQ; ++w) {
    const unsigned zf = (unsigned)C.zfreq[w];
    float v = stf[(zf << 10) | (unsigned)t];
    acc[w] = (__popc((unsigned)C.zm[w] & (unsigned)t) & 1) ? -v : v;
  }
  #pragma unroll
  for (int w = 0; w < NQ; ++w) {
    #pragma unroll
    for (int off = 32; off > 0; off >>= 1)
      acc[w] += __shfl_xor(acc[w], off, 64);
  }
  __syncthreads();
  const int lane = t & 63, wid = t >> 6;   // wid in 0..15
  if (lane == 0) {
    #pragma unroll
    for (int w = 0; w < NQ; ++w) stf[wid * NQ + w] = acc[w];
  }
  __syncthreads();
  if (t < NQ) {
    float tot = 0.f;
    #pragma unroll
    for (int k = 0; k < 16; ++k) tot += stf[k * NQ + t];
    float s2v;
    if constexpr (USE_WS) {
      s2v = *s2p;
    } else {
      double pr = 1.0;
      for (int j = NQ; j < DEPTH * NQ; ++j) {
        float ss, cc; sincosf(0.5f * theta[j], &ss, &cc);
        pr *= (double)cc * (double)cc;
      }
      s2v = (float)pr;
    }
    out[s * NQ + t] = tot * s2v;
  }
}

// ---------- prep: precise trig tables + deferred-scale into workspace ----------
// ws float layout: [0,224) tt (c,s) pairs; [256,480) tq (t,c) pairs; [512] S^2
__global__ void prep_kernel(const float* __restrict__ inp,
                            const float* __restrict__ theta,
                            float* __restrict__ ws, float4* __restrict__ albe,
                            int nAlbe) {
  const int i = blockIdx.x * 256 + threadIdx.x;
  float2* tt = (float2*)ws;
  float2* tq = (float2*)(ws + 256);
  if (i < DEPTH * NQ) {
    float ss, cc; sincosf(0.5f * theta[i], &ss, &cc);
    tt[i] = make_float2(cc, ss);
    float ca = (fabsf(cc) < 1e-20f) ? copysignf(1e-20f, cc) : cc;
    tq[i] = make_float2(ss / ca, ca);
  }
  if (i == 0) {
    double pr = 1.0;
    for (int j = NQ; j < DEPTH * NQ; ++j) {
      double cc = cos(0.5 * (double)theta[j]);
      pr *= cc * cc;
    }
    ws[512] = (float)pr;
  }
  if (albe != nullptr && i < nAlbe) {
    const int w = i % NQ;
    float sx, cx; sincosf(0.5f * inp[i], &sx, &cx);
    float stt, ctt; sincosf(0.5f * theta[w], &stt, &ctt);
    albe[i] = make_float4(ctt * cx, stt * sx, stt * cx, -ctt * sx);
  }
}

// ---------- host: GF(2) linear algebra for the CNOT-ring permutation ----------
static inline unsigned ffwd(unsigned x) {
  unsigned t = x;
  t ^= t >> 1; t ^= t >> 2; t ^= t >> 4; t ^= t >> 8;
  unsigned y = t & 0x1FFFu;
  y |= (((t >> 13) ^ t) & 1u) << 13;
  return y;
}
static inline unsigned finv(unsigned y) {
  unsigned x = 0;
  for (int j = 0; j <= 11; ++j) x |= (((y >> j) ^ (y >> (j + 1))) & 1u) << j;
  x |= (((y >> 12) ^ (y >> 13) ^ y) & 1u) << 12;
  x |= (((y >> 13) ^ y) & 1u) << 13;
  return x;
}
static inline int rank3n(unsigned a, unsigned b, unsigned c) {
  unsigned bas[4] = {0, 0, 0, 0};
  unsigned vv[3] = {a & 15u, b & 15u, c & 15u};
  int r = 0;
  for (int i = 0; i < 3; ++i) {
    unsigned u = vv[i];
    for (int bit = 3; bit >= 0; --bit)
      if (((u >> bit) & 1u) && bas[bit]) u ^= bas[bit];
    if (u) { bas[31 - __builtin_clz(u)] = u; ++r; }
  }
  return r;
}
static inline unsigned phi_full(unsigned m, const unsigned* ac) {
  unsigned d = 0;
  for (int j = 0; j < 8; ++j)
    if ((m >> (6 + j)) & 1u) d ^= ac[j];
  return m ^ d;
}
static inline int par(unsigned x) { return __builtin_popcount(x) & 1; }

static int scoreA(const unsigned* ac, const u16 am[14][7], int bail) {
  int s = 0;
  for (int p = 0; p < 14; ++p) {
    unsigned pm[7];
    for (int i = 0; i < 7; ++i) pm[i] = phi_full((unsigned)am[p][i], ac) & 15u;
    int best = 0;
    for (int x = 0; x < 7 && best < 3; ++x)
      for (int y = x + 1; y < 7 && best < 3; ++y)
        for (int z = y + 1; z < 7 && best < 3; ++z) {
          int r = rank3n(pm[x], pm[y], pm[z]);
          if (r > best) best = r;
        }
    if (best < 3) s += 3 - best;
    if (s >= bail) return s;
  }
  return s;
}

extern "C" void kernel_launch(void* const* d_in, const int* in_sizes, int n_in,
                              void* d_out, int out_size, void* d_ws, size_t ws_size,
                              hipStream_t stream) {
  const float* inp = (const float*)d_in[0];
  const float* theta = (const float*)d_in[1];
  float* out = (float*)d_out;
  const int batch = in_sizes[0] / NQ;

  // ---- collect per-pass wire masks (K cols) and sign rows (L rows)
  u16 Lc[NQ], Kc[NQ];
  u16 allmask[14][7]; unsigned allrow[14][7];
  u16 zrow[NQ];
  for (int j = 0; j < NQ; ++j) { Lc[j] = (u16)(1u << j); Kc[j] = (u16)(1u << j); }
  for (int d = 1; d <= 8; ++d) {
    u16 nL[NQ], nK[NQ];
    for (int j = 0; j < NQ; ++j) nL[j] = (u16)ffwd((unsigned)Lc[j]);
    for (int j = 0; j < NQ; ++j) {
      unsigned fj = finv(1u << j);
      unsigned v = 0;
      for (int b = 0; b < NQ; ++b) if ((fj >> b) & 1u) v ^= Kc[b];
      nK[j] = (u16)v;
    }
    for (int j = 0; j < NQ; ++j) { Lc[j] = nL[j]; Kc[j] = nK[j]; }

    if (d <= 7) {
      for (int pg = 0; pg < 2; ++pg) {
        const int p = (d - 1) * 2 + pg;
        const int wbase = pg * 7;
        for (int i = 0; i < 7; ++i) {
          const int bit = 13 - (wbase + i);
          allmask[p][i] = Kc[bit];
          unsigned r = 0;
          for (int j = 0; j < NQ; ++j) r |= ((unsigned)(Lc[j] >> bit) & 1u) << j;
          allrow[p][i] = r;
        }
      }
    } else {
      for (int w = 0; w < NQ; ++w) {
        const int bit = 13 - w;
        unsigned r = 0;
        for (int j = 0; j < NQ; ++j) r |= ((unsigned)(Lc[j] >> bit) & 1u) << j;
        zrow[w] = (u16)r;
      }
    }
  }

  // ---- search layout map A (8 cols -> low4) so every pass has a rank-3 triple
  unsigned acol[8] = {0, 0, 0, 0, 0, 0, 0, 0};
  int bestSc = scoreA(acol, allmask, 1 << 30);
  if (bestSc > 0) {
    unsigned long long seed = 88172645463325252ULL;
    for (int it = 0; it < 20000 && bestSc > 0; ++it) {
      unsigned cand[8];
      for (int j = 0; j < 8; ++j) {
        seed ^= seed << 13; seed ^= seed >> 7; seed ^= seed << 17;
        cand[j] = (unsigned)(seed & 15u);
      }
      int sc = scoreA(cand, allmask, bestSc);
      if (sc < bestSc) {
        bestSc = sc;
        for (int j = 0; j < 8; ++j) acol[j] = cand[j];
      }
    }
  }

  // ---- build pass constants
  SimConsts C;
  u16 mkLast[4] = {0, 0, 0, 0};
  unsigned lcolLast[10] = {0};
  for (int p = 0; p < 14; ++p) {
    PassK& P = C.pass[p];
    const int pg = p & 1, wbase = pg * 7;

    unsigned pm[7];
    for (int i = 0; i < 7; ++i) pm[i] = phi_full((unsigned)allmask[p][i], acol) & 15u;
    int ca = 0, cb = 1, cc2 = 2, best = -1;
    for (int x = 0; x < 7; ++x)
      for (int y = x + 1; y < 7; ++y)
        for (int z = y + 1; z < 7; ++z) {
          int r = rank3n(pm[x], pm[y], pm[z]);
          if (r > best) { best = r; ca = x; cb = y; cc2 = z; }
        }

    unsigned cmL[3] = {allmask[p][ca], allmask[p][cb], allmask[p][cc2]};
    unsigned srowAll[7];
    srowAll[4] = allrow[p][ca]; srowAll[5] = allrow[p][cb]; srowAll[6] = allrow[p][cc2];
    P.widx[4] = (u16)(wbase + ca); P.widx[5] = (u16)(wbase + cb);
    P.widx[6] = (u16)(wbase + cc2);
    u16 mk[4]; int ii = 0;
    for (int i = 0; i < 7; ++i)
      if (i != ca && i != cb && i != cc2) {
        mk[ii] = allmask[p][i]; srowAll[ii] = allrow[p][i];
        P.widx[ii] = (u16)(wbase + i); ++ii;
      }
    if (p == 13) for (int i = 0; i < 4; ++i) mkLast[i] = mk[i];

    // full-rank (14-dim) independence tracker
    unsigned red[14] = {0};
    auto tryAdd = [&](unsigned x) -> bool {
      while (x) {
        int h = 31 - __builtin_clz(x);
        if (!red[h]) { red[h] = x; return true; }
        x ^= red[h];
      }
      return false;
    };
    for (int i = 0; i < 7; ++i) tryAdd((unsigned)allmask[p][i]);

    // physical low4 span of the cross triple
    unsigned nb[4] = {0, 0, 0, 0};
    for (int i = 0; i < 3; ++i) {
      unsigned u = pm[i == 0 ? ca : (i == 1 ? cb : cc2)];
      for (int bit = 3; bit >= 0; --bit)
        if (((u >> bit) & 1u) && nb[bit]) u ^= nb[bit];
      if (u) nb[31 - __builtin_clz(u)] = u;
    }
    // target low4 for scol0: smallest value outside the span
    unsigned uTarget = 0;
    for (unsigned v = 1; v < 16; ++v) {
      unsigned r = v;
      for (int bit = 3; bit >= 0; --bit)
        if (((r >> bit) & 1u) && nb[bit]) r ^= nb[bit];
      if (r) { uTarget = v; break; }
    }
    unsigned scol[7];
    {
      bool ok = false;
      for (unsigned h = 0; h < 256u && !ok; ++h) {
        unsigned d4 = 0;
        for (int j = 0; j < 8; ++j) if ((h >> j) & 1u) d4 ^= acol[j];
        unsigned v = ((uTarget ^ d4) & 15u) | (h << 6);
        if (v && tryAdd(v)) { scol[0] = v; ok = true; }
      }
      for (unsigned cand = 1; cand < 16384u && !ok; ++cand)
        if (tryAdd(cand)) { scol[0] = cand; ok = true; }
    }
    for (int i2 = 1; i2 < 7; ++i2) {
      bool ok = false;
      for (unsigned h = 1; h < 256u && !ok; ++h)
        if (tryAdd(h << 6)) { scol[i2] = h << 6; ok = true; }
      for (unsigned cand = 1; cand < 16384u && !ok; ++cand)
        if (tryAdd(cand)) { scol[i2] = cand; ok = true; }
    }

    unsigned lcol[10] = {cmL[0], cmL[1], scol[0], cmL[2],
                         scol[1], scol[2], scol[3], scol[4], scol[5], scol[6]};
    for (int b = 0; b < 10; ++b) P.pcol[b] = (u16)phi_full(lcol[b], acol);
    if (p == 13) for (int b = 0; b < 10; ++b) lcolLast[b] = lcol[b];

    for (int i = 0; i < 7; ++i) {
      unsigned m = 0;
      for (int b = 0; b < 10; ++b)
        m |= (unsigned)par(srowAll[i] & lcol[b]) << b;
      P.sm[i] = (u16)m;
    }
    for (int e = 0; e < 16; ++e) {
      unsigned v = 0;
      for (int i = 0; i < 4; ++i)
        if ((e >> i) & 1) v ^= (unsigned)mk[i];
      P.pxm[e] = (u16)phi_full(v, acol);
    }
  }

  // measurement constants (last-pass basis)
  for (int w = 0; w < NQ; ++w) {
    unsigned zf = 0;
    for (int i = 0; i < 4; ++i)
      zf |= (unsigned)par((unsigned)zrow[w] & (unsigned)mkLast[i]) << i;
    C.zfreq[w] = (u16)zf;
    unsigned m = 0;
    for (int b = 0; b < 10; ++b)
      m |= (unsigned)par((unsigned)zrow[w] & lcolLast[b]) << b;
    C.zm[w] = (u16)m;
  }
  // init-write Phi deltas
  for (int e = 0; e < 16; ++e) {
    unsigned d4 = 0;
    for (int k = 0; k < 4; ++k)
      if ((e >> k) & 1) d4 ^= acol[4 + k];
    C.de[e] = (u16)d4;
  }
  for (int j = 0; j < 4; ++j) C.dcolw[j] = (u16)acol[j];

  // ws float layout: [0,224) tt; [256,480) tq; [512] S2; albe from byte 4096
  const size_t needT = 4096;
  const size_t needA = 4096 + (size_t)batch * NQ * sizeof(float4);
  const bool useT = ws_size >= needT;
  const bool useA = useT && ws_size >= needA;
  float* wsf = (float*)d_ws;
  float2* tt = (float2*)wsf;
  float2* tq = (float2*)(wsf + 256);
  float* s2p = wsf + 512;
  float4* albe = (float4*)((char*)d_ws + 4096);

  if (useT) {
    const int nAlbe = useA ? batch * NQ : 0;
    const int nwork = useA ? nAlbe : DEPTH * NQ;
    prep_kernel<<<(nwork + 255) / 256, 256, 0, stream>>>(
        inp, theta, wsf, useA ? albe : nullptr, nAlbe);
    qsim_kernel<true><<<batch, TPB, 0, stream>>>(inp, theta, out, tt, tq, s2p,
                                                 albe, useA ? 1 : 0, C);
  } else {
    qsim_kernel<false><<<batch, TPB, 0, stream>>>(inp, theta, out, nullptr,
                                                  nullptr, nullptr, nullptr, 0, C);
  }
}

// Round 14
// 176.568 us; speedup vs baseline: 1.0951x; 1.0951x over previous
//
#include <hip/hip_runtime.h>

typedef unsigned short u16;
typedef float f2 __attribute__((ext_vector_type(2)));

#define NQ 14
#define NSTATE (1 << NQ)   // 16384
#define DEPTH 8
#define TPB 1024
#define NPASS 14

// ---------- host-side constants passed by value ----------
struct PassK {
  u16 pcol[10];    // PHYSICAL rep columns for t bits 0..9
  u16 sm[7];       // sign masks over t; slots 0..3 in-reg, 4..6 cross
  u16 widx[7];     // within-layer theta index per slot (0..13)
  u16 pxm[16];     // PHYSICAL xm (XOR combos of in-reg masks, mapped by Phi)
};

struct SimConsts {
  PassK pass[NPASS];  // layers 1..7 x two 7-wire passes
  u16 zm[14];      // measurement sign masks over t (last-pass basis)
  u16 zfreq[14];   // 4-bit WHT frequency per wire (last-pass mask basis)
  u16 de[16];      // init-write address delta per e (Phi correction)
  u16 dcolw[4];    // init-write delta columns for t bits 6..9
};

// ---------- device ----------
__device__ __forceinline__ f2 cmulv(f2 a, f2 b) {
  f2 r;
  r.x = a.x * b.x - a.y * b.y;
  r.y = a.x * b.y + a.y * b.x;
  return r;
}

// Packed in-register butterfly (fallback path): xn = x - t*y ; yn = y + t*x.
__device__ __forceinline__ void bfly_pk(f2& x, f2& y, f2 tp, f2 tn) {
  f2 xn, yn;
  asm("v_pk_fma_f32 %0, %4, %3, %2\n\t"   // xn = tn*y + x
      "v_pk_fma_f32 %1, %5, %2, %3"       // yn = tp*x + y
      : "=&v"(xn), "=&v"(yn)
      : "v"(x), "v"(y), "v"(tn), "v"(tp));
  x = xn; y = yn;
}

// Fused cross-wire butterfly: a += tg * partner(a), partner via DPP on src0.
// s_nop 1 covers the 2-wait-state VALU-write -> DPP-read hazard.
// Non-volatile: data deps are via operands; scheduler may interleave.
__device__ __forceinline__ void xfmac_l1(f2& v, float tg) {   // partner lane^1
  float x = v.x, y = v.y;
  asm("s_nop 1\n\t"
      "v_fmac_f32_dpp %0, %0, %2 quad_perm:[1,0,3,2] row_mask:0xf bank_mask:0xf\n\t"
      "v_fmac_f32_dpp %1, %1, %2 quad_perm:[1,0,3,2] row_mask:0xf bank_mask:0xf"
      : "+v"(x), "+v"(y) : "v"(tg));
  v.x = x; v.y = y;
}
__device__ __forceinline__ void xfmac_l2(f2& v, float tg) {   // partner lane^2
  float x = v.x, y = v.y;
  asm("s_nop 1\n\t"
      "v_fmac_f32_dpp %0, %0, %2 quad_perm:[2,3,0,1] row_mask:0xf bank_mask:0xf\n\t"
      "v_fmac_f32_dpp %1, %1, %2 quad_perm:[2,3,0,1] row_mask:0xf bank_mask:0xf"
      : "+v"(x), "+v"(y) : "v"(tg));
  v.x = x; v.y = y;
}
__device__ __forceinline__ void xfmac_l8(f2& v, float tg) {   // partner lane^8
  float x = v.x, y = v.y;
  asm("s_nop 1\n\t"
      "v_fmac_f32_dpp %0, %0, %2 row_ror:8 row_mask:0xf bank_mask:0xf\n\t"
      "v_fmac_f32_dpp %1, %1, %2 row_ror:8 row_mask:0xf bank_mask:0xf"
      : "+v"(x), "+v"(y) : "v"(tg));
  v.x = x; v.y = y;
}

// ---- TABLE-mode pass: tg[7] + rep come from the precomputed record.
// 4 wires in-register (plain C butterflies) + 3 via fused DPP-fmac.
template <bool WRITE>
__device__ __forceinline__ void ry7t(f2* st, const u16* pxm,
                                     float4 v0, float4 v1, f2* a) {
  const unsigned rep = __float_as_uint(v1.w);
  const unsigned base = rep << 3;
  unsigned ad[16];
  #pragma unroll
  for (int e = 0; e < 16; ++e)
    ad[e] = base ^ (((unsigned)pxm[e]) << 3);   // pxm<<3 uniform (SGPR)

  #pragma unroll
  for (int e = 0; e < 16; ++e) a[e] = *(const f2*)((const char*)st + ad[e]);

  // cross slot 4: partner = lane^1
  #pragma unroll
  for (int e = 0; e < 16; ++e) xfmac_l1(a[e], v1.x);
  // 4 in-register wires (tangent butterflies, plain C)
  float tgr[4] = {v0.x, v0.y, v0.z, v0.w};
  #pragma unroll
  for (int i = 0; i < 4; ++i) {
    const float ti = tgr[i];
    #pragma unroll
    for (int e = 0; e < 16; ++e) {
      if (!(e & (1 << i))) {
        f2 xe = a[e], ye = a[e | (1 << i)];
        a[e]            = xe - ti * ye;
        a[e | (1 << i)] = ye + ti * xe;
      }
    }
  }
  // cross slot 5: partner = lane^2
  #pragma unroll
  for (int e = 0; e < 16; ++e) xfmac_l2(a[e], v1.y);
  // cross slot 6: partner = lane^8
  #pragma unroll
  for (int e = 0; e < 16; ++e) xfmac_l8(a[e], v1.z);

  if constexpr (WRITE) {
    #pragma unroll
    for (int e = 0; e < 16; ++e) *(f2*)((char*)st + ad[e]) = a[e];
  }
}

// ---- FALLBACK pass (no table): R13's verified path.
template <bool USE_WS, bool WRITE>
__device__ __forceinline__ void ry7x(f2* st, const PassK& P, const float* th,
                                     const float2* tqd, int t, f2* a) {
  const unsigned wv = __builtin_amdgcn_readfirstlane(((unsigned)t) >> 6);
  unsigned rep = 0;
  #pragma unroll
  for (int j = 0; j < 4; ++j)
    rep ^= ((wv >> j) & 1u) ? (unsigned)P.pcol[6 + j] : 0u;
  #pragma unroll
  for (int b = 0; b < 6; ++b)
    rep ^= ((t >> b) & 1u) ? (unsigned)P.pcol[b] : 0u;

  float tv[7];
  #pragma unroll
  for (int i = 0; i < 7; ++i) {
    if constexpr (USE_WS) {
      tv[i] = tqd[P.widx[i]].x;
    } else {
      float ss, cc; __sincosf(0.5f * th[P.widx[i]], &ss, &cc);
      float ca = (fabsf(cc) < 1e-20f) ? copysignf(1e-20f, cc) : cc;
      tv[i] = ss / ca;
    }
  }
  float tg[7];
  #pragma unroll
  for (int i = 0; i < 4; ++i)
    tg[i] = (__popc((unsigned)P.sm[i] & (unsigned)t) & 1) ? -tv[i] : tv[i];
  #pragma unroll
  for (int i = 4; i < 7; ++i)
    tg[i] = (__popc((unsigned)P.sm[i] & (unsigned)t) & 1) ? tv[i] : -tv[i];

  const unsigned base = rep << 3;
  unsigned ad[16];
  #pragma unroll
  for (int e = 0; e < 16; ++e)
    ad[e] = base ^ (((unsigned)P.pxm[e]) << 3);

  #pragma unroll
  for (int e = 0; e < 16; ++e) a[e] = *(const f2*)((const char*)st + ad[e]);

  #pragma unroll
  for (int e = 0; e < 16; ++e) xfmac_l1(a[e], tg[4]);
  #pragma unroll
  for (int i = 0; i < 4; ++i) {
    f2 tp, tn;
    tp.x = tg[i]; tp.y = tg[i];
    tn.x = -tg[i]; tn.y = -tg[i];
    #pragma unroll
    for (int e = 0; e < 16; ++e) {
      if (!(e & (1 << i))) bfly_pk(a[e], a[e | (1 << i)], tp, tn);
    }
  }
  #pragma unroll
  for (int e = 0; e < 16; ++e) xfmac_l2(a[e], tg[5]);
  #pragma unroll
  for (int e = 0; e < 16; ++e) xfmac_l8(a[e], tg[6]);

  if constexpr (WRITE) {
    #pragma unroll
    for (int e = 0; e < 16; ++e) *(f2*)((char*)st + ad[e]) = a[e];
  }
}

// ---- shared init + measurement bodies (macro-free, inlined twice) ----
__device__ __forceinline__ void init_state(f2* st, f2* a, const f2* A,
                                           const f2* B, int t,
                                           const SimConsts& C) {
  f2 rhi; rhi.x = 1.f; rhi.y = 0.f;
  #pragma unroll
  for (int b = 0; b < 10; ++b) {           // p bit b <- t bit b, wire 13-b
    const int w = 13 - b;
    f2 f = ((t >> b) & 1) ? B[w] : A[w];
    rhi = cmulv(rhi, f);
  }
  a[0] = rhi;
  #pragma unroll
  for (int k = 0; k < 4; ++k) {            // e bit k <-> p bit 10+k <-> wire 3-k
    const int w = 3 - k;
    const int sz = 1 << k;
    #pragma unroll
    for (int j = 0; j < 8; ++j) {
      if (j < sz) {
        f2 v = a[j];
        a[j]      = cmulv(v, A[w]);
        a[j + sz] = cmulv(v, B[w]);
      }
    }
  }
  unsigned dw = 0;
  #pragma unroll
  for (int j = 0; j < 4; ++j)
    dw ^= ((t >> (6 + j)) & 1u) ? (unsigned)C.dcolw[j] : 0u;
  #pragma unroll
  for (int e = 0; e < 16; ++e)
    st[(((unsigned)e << 10) | (unsigned)t) ^ (unsigned)C.de[e] ^ dw] = a[e];
}

__device__ __forceinline__ void measure_out(f2* st, f2* a, int s, int t,
                                            float s2v, float* out,
                                            const SimConsts& C) {
  float pv[16];
  #pragma unroll
  for (int e = 0; e < 16; ++e) pv[e] = a[e].x * a[e].x + a[e].y * a[e].y;
  #pragma unroll
  for (int s4 = 0; s4 < 4; ++s4) {
    const int step = 1 << s4;
    #pragma unroll
    for (int e = 0; e < 16; ++e) {
      if (!(e & step)) {
        float x = pv[e], y = pv[e | step];
        pv[e] = x + y; pv[e | step] = x - y;
      }
    }
  }
  float* stf = (float*)st;
  #pragma unroll
  for (int e = 0; e < 16; ++e) stf[(e << 10) | t] = pv[e];
  __syncthreads();

  float acc[NQ];
  #pragma unroll
  for (int w = 0; w < NQ; ++w) {
    const unsigned zf = (unsigned)C.zfreq[w];
    float v = stf[(zf << 10) | (unsigned)t];
    acc[w] = (__popc((unsigned)C.zm[w] & (unsigned)t) & 1) ? -v : v;
  }
  #pragma unroll
  for (int w = 0; w < NQ; ++w) {
    #pragma unroll
    for (int off = 32; off > 0; off >>= 1)
      acc[w] += __shfl_xor(acc[w], off, 64);
  }
  __syncthreads();
  const int lane = t & 63, wid = t >> 6;   // wid in 0..15
  if (lane == 0) {
    #pragma unroll
    for (int w = 0; w < NQ; ++w) stf[wid * NQ + w] = acc[w];
  }
  __syncthreads();
  if (t < NQ) {
    float tot = 0.f;
    #pragma unroll
    for (int k = 0; k < 16; ++k) tot += stf[k * NQ + t];
    out[s * NQ + t] = tot * s2v;
  }
}

// ---- TABLE-mode main kernel ----
__global__ __launch_bounds__(TPB, 1) void qsim_tbl_kernel(
    const float* __restrict__ inp, const float* __restrict__ theta,
    float* __restrict__ out, const float2* __restrict__ tt,
    const float* __restrict__ s2p, const float4* __restrict__ albe,
    int use_albe, const float4* __restrict__ tbl, SimConsts C) {
  __shared__ f2 st[NSTATE];   // 128 KiB
  const int s = blockIdx.x;
  const int t = threadIdx.x;

  // prefetch pass-0 record early (hides under init)
  float4 c0 = tbl[(size_t)t * 2];
  float4 c1 = tbl[(size_t)t * 2 + 1];

  f2 A[NQ], B[NQ];
  if (use_albe) {
    #pragma unroll
    for (int w = 0; w < NQ; ++w) {
      float4 v = albe[s * NQ + w];       // uniform -> s_load_dwordx4
      A[w].x = v.x; A[w].y = v.y;
      B[w].x = v.z; B[w].y = v.w;
    }
  } else {
    #pragma unroll
    for (int w = 0; w < NQ; ++w) {
      float sx, cx; __sincosf(0.5f * inp[s * NQ + w], &sx, &cx);
      float2 tvv = tt[w];
      A[w].x = tvv.x * cx; A[w].y = tvv.y * sx;
      B[w].x = tvv.y * cx; B[w].y = -tvv.x * sx;
    }
  }

  f2 a[16];
  init_state(st, a, A, B, t, C);
  __syncthreads();

  // passes 0..12 (write), software-pipelined table loads
  #pragma unroll 1
  for (int p = 0; p < NPASS - 1; ++p) {
    float4 n0, n1;
    {
      const float4* nb = tbl + ((size_t)(p + 1) * 1024 + (size_t)t) * 2;
      n0 = nb[0]; n1 = nb[1];
    }
    ry7t<true>(st, C.pass[p].pxm, c0, c1, a);
    __syncthreads();
    c0 = n0; c1 = n1;
  }
  // pass 13: keep results in registers, fuse measurement
  ry7t<false>(st, C.pass[NPASS - 1].pxm, c0, c1, a);
  __syncthreads();

  measure_out(st, a, s, t, *s2p, out, C);
}

// ---- FALLBACK main kernel (R13 path) ----
template <bool USE_WS>
__global__ __launch_bounds__(TPB, 1) void qsim_kernel(
    const float* __restrict__ inp, const float* __restrict__ theta,
    float* __restrict__ out, const float2* __restrict__ tt,
    const float2* __restrict__ tq, const float* __restrict__ s2p,
    const float4* __restrict__ albe, int use_albe, SimConsts C) {
  __shared__ f2 st[NSTATE];
  const int s = blockIdx.x;
  const int t = threadIdx.x;

  f2 A[NQ], B[NQ];
  if constexpr (USE_WS) {
    if (use_albe) {
      #pragma unroll
      for (int w = 0; w < NQ; ++w) {
        float4 v = albe[s * NQ + w];
        A[w].x = v.x; A[w].y = v.y;
        B[w].x = v.z; B[w].y = v.w;
      }
    } else {
      #pragma unroll
      for (int w = 0; w < NQ; ++w) {
        float sx, cx; __sincosf(0.5f * inp[s * NQ + w], &sx, &cx);
        float2 tvv = tt[w];
        A[w].x = tvv.x * cx; A[w].y = tvv.y * sx;
        B[w].x = tvv.y * cx; B[w].y = -tvv.x * sx;
      }
    }
  } else {
    #pragma unroll
    for (int w = 0; w < NQ; ++w) {
      float sx, cx; __sincosf(0.5f * inp[s * NQ + w], &sx, &cx);
      float stt, ctt; __sincosf(0.5f * theta[w], &stt, &ctt);
      A[w].x = ctt * cx; A[w].y = stt * sx;
      B[w].x = stt * cx; B[w].y = -ctt * sx;
    }
  }

  f2 a[16];
  init_state(st, a, A, B, t, C);
  __syncthreads();

  #pragma unroll 1
  for (int d = 1; d <= 6; ++d) {
    const float* th = theta + d * NQ;
    const float2* tqd = USE_WS ? (tq + d * NQ) : nullptr;
    ry7x<USE_WS, true>(st, C.pass[(d - 1) * 2 + 0], th, tqd, t, a);
    __syncthreads();
    ry7x<USE_WS, true>(st, C.pass[(d - 1) * 2 + 1], th, tqd, t, a);
    __syncthreads();
  }
  {
    const float* th = theta + 7 * NQ;
    const float2* tqd = USE_WS ? (tq + 7 * NQ) : nullptr;
    ry7x<USE_WS, true>(st, C.pass[12], th, tqd, t, a);
    __syncthreads();
    ry7x<USE_WS, false>(st, C.pass[13], th, tqd, t, a);
  }
  __syncthreads();

  float s2v;
  if constexpr (USE_WS) {
    s2v = *s2p;
  } else {
    double pr = 1.0;
    for (int j = NQ; j < DEPTH * NQ; ++j) {
      float ss, cc; sincosf(0.5f * theta[j], &ss, &cc);
      pr *= (double)cc * (double)cc;
    }
    s2v = (float)pr;
  }
  measure_out(st, a, s, t, s2v, out, C);
}

// ---------- prep: trig tables + deferred scale + tg/rep table ----------
// ws float layout: [0,224) tt; [256,480) tq; [512] S2; tbl at byte 8192
__global__ void prep_kernel(const float* __restrict__ inp,
                            const float* __restrict__ theta,
                            float* __restrict__ ws, float4* __restrict__ tbl,
                            float4* __restrict__ albe, int nAlbe, SimConsts C) {
  const int i = blockIdx.x * 256 + threadIdx.x;
  float2* tt = (float2*)ws;
  float2* tq = (float2*)(ws + 256);
  if (i < DEPTH * NQ) {
    float ss, cc; sincosf(0.5f * theta[i], &ss, &cc);
    tt[i] = make_float2(cc, ss);
    float ca = (fabsf(cc) < 1e-20f) ? copysignf(1e-20f, cc) : cc;
    tq[i] = make_float2(ss / ca, ca);
  }
  if (i == 0) {
    double pr = 1.0;
    for (int j = NQ; j < DEPTH * NQ; ++j) {
      double cc = cos(0.5 * (double)theta[j]);
      pr *= cc * cc;
    }
    ws[512] = (float)pr;
  }
  if (tbl != nullptr && i < NPASS * 1024) {
    const int p = i >> 10, t = i & 1023;
    const PassK& P = C.pass[p];
    const int d = (p >> 1) + 1;
    float tg[7];
    #pragma unroll
    for (int k = 0; k < 7; ++k) {
      float ss, cc; sincosf(0.5f * theta[d * NQ + P.widx[k]], &ss, &cc);
      float ca = (fabsf(cc) < 1e-20f) ? copysignf(1e-20f, cc) : cc;
      float tv = ss / ca;
      int sg = __popc((unsigned)P.sm[k] & (unsigned)t) & 1;
      tg[k] = (k < 4) ? (sg ? -tv : tv) : (sg ? tv : -tv);
    }
    unsigned rep = 0;
    #pragma unroll
    for (int b = 0; b < 10; ++b)
      rep ^= ((t >> b) & 1u) ? (unsigned)P.pcol[b] : 0u;
    tbl[(size_t)i * 2]     = make_float4(tg[0], tg[1], tg[2], tg[3]);
    tbl[(size_t)i * 2 + 1] = make_float4(tg[4], tg[5], tg[6],
                                         __uint_as_float(rep));
  }
  if (albe != nullptr && i < nAlbe) {
    const int w = i % NQ;
    float sx, cx; sincosf(0.5f * inp[i], &sx, &cx);
    float stt, ctt; sincosf(0.5f * theta[w], &stt, &ctt);
    albe[i] = make_float4(ctt * cx, stt * sx, stt * cx, -ctt * sx);
  }
}

// ---------- host: GF(2) linear algebra for the CNOT-ring permutation ----------
static inline unsigned ffwd(unsigned x) {
  unsigned t = x;
  t ^= t >> 1; t ^= t >> 2; t ^= t >> 4; t ^= t >> 8;
  unsigned y = t & 0x1FFFu;
  y |= (((t >> 13) ^ t) & 1u) << 13;
  return y;
}
static inline unsigned finv(unsigned y) {
  unsigned x = 0;
  for (int j = 0; j <= 11; ++j) x |= (((y >> j) ^ (y >> (j + 1))) & 1u) << j;
  x |= (((y >> 12) ^ (y >> 13) ^ y) & 1u) << 12;
  x |= (((y >> 13) ^ y) & 1u) << 13;
  return x;
}
static inline int rank3n(unsigned a, unsigned b, unsigned c) {
  unsigned bas[4] = {0, 0, 0, 0};
  unsigned vv[3] = {a & 15u, b & 15u, c & 15u};
  int r = 0;
  for (int i = 0; i < 3; ++i) {
    unsigned u = vv[i];
    for (int bit = 3; bit >= 0; --bit)
      if (((u >> bit) & 1u) && bas[bit]) u ^= bas[bit];
    if (u) { bas[31 - __builtin_clz(u)] = u; ++r; }
  }
  return r;
}
static inline unsigned phi_full(unsigned m, const unsigned* ac) {
  unsigned d = 0;
  for (int j = 0; j < 8; ++j)
    if ((m >> (6 + j)) & 1u) d ^= ac[j];
  return m ^ d;
}
static inline int par(unsigned x) { return __builtin_popcount(x) & 1; }

static int scoreA(const unsigned* ac, const u16 am[14][7], int bail) {
  int s = 0;
  for (int p = 0; p < 14; ++p) {
    unsigned pm[7];
    for (int i = 0; i < 7; ++i) pm[i] = phi_full((unsigned)am[p][i], ac) & 15u;
    int best = 0;
    for (int x = 0; x < 7 && best < 3; ++x)
      for (int y = x + 1; y < 7 && best < 3; ++y)
        for (int z = y + 1; z < 7 && best < 3; ++z) {
          int r = rank3n(pm[x], pm[y], pm[z]);
          if (r > best) best = r;
        }
    if (best < 3) s += 3 - best;
    if (s >= bail) return s;
  }
  return s;
}

extern "C" void kernel_launch(void* const* d_in, const int* in_sizes, int n_in,
                              void* d_out, int out_size, void* d_ws, size_t ws_size,
                              hipStream_t stream) {
  const float* inp = (const float*)d_in[0];
  const float* theta = (const float*)d_in[1];
  float* out = (float*)d_out;
  const int batch = in_sizes[0] / NQ;

  // ---- collect per-pass wire masks (K cols) and sign rows (L rows)
  u16 Lc[NQ], Kc[NQ];
  u16 allmask[14][7]; unsigned allrow[14][7];
  u16 zrow[NQ];
  for (int j = 0; j < NQ; ++j) { Lc[j] = (u16)(1u << j); Kc[j] = (u16)(1u << j); }
  for (int d = 1; d <= 8; ++d) {
    u16 nL[NQ], nK[NQ];
    for (int j = 0; j < NQ; ++j) nL[j] = (u16)ffwd((unsigned)Lc[j]);
    for (int j = 0; j < NQ; ++j) {
      unsigned fj = finv(1u << j);
      unsigned v = 0;
      for (int b = 0; b < NQ; ++b) if ((fj >> b) & 1u) v ^= Kc[b];
      nK[j] = (u16)v;
    }
    for (int j = 0; j < NQ; ++j) { Lc[j] = nL[j]; Kc[j] = nK[j]; }

    if (d <= 7) {
      for (int pg = 0; pg < 2; ++pg) {
        const int p = (d - 1) * 2 + pg;
        const int wbase = pg * 7;
        for (int i = 0; i < 7; ++i) {
          const int bit = 13 - (wbase + i);
          allmask[p][i] = Kc[bit];
          unsigned r = 0;
          for (int j = 0; j < NQ; ++j) r |= ((unsigned)(Lc[j] >> bit) & 1u) << j;
          allrow[p][i] = r;
        }
      }
    } else {
      for (int w = 0; w < NQ; ++w) {
        const int bit = 13 - w;
        unsigned r = 0;
        for (int j = 0; j < NQ; ++j) r |= ((unsigned)(Lc[j] >> bit) & 1u) << j;
        zrow[w] = (u16)r;
      }
    }
  }

  // ---- search layout map A (8 cols -> low4) so every pass has a rank-3 triple
  unsigned acol[8] = {0, 0, 0, 0, 0, 0, 0, 0};
  int bestSc = scoreA(acol, allmask, 1 << 30);
  if (bestSc > 0) {
    unsigned long long seed = 88172645463325252ULL;
    for (int it = 0; it < 20000 && bestSc > 0; ++it) {
      unsigned cand[8];
      for (int j = 0; j < 8; ++j) {
        seed ^= seed << 13; seed ^= seed >> 7; seed ^= seed << 17;
        cand[j] = (unsigned)(seed & 15u);
      }
      int sc = scoreA(cand, allmask, bestSc);
      if (sc < bestSc) {
        bestSc = sc;
        for (int j = 0; j < 8; ++j) acol[j] = cand[j];
      }
    }
  }

  // ---- build pass constants
  SimConsts C;
  u16 mkLast[4] = {0, 0, 0, 0};
  unsigned lcolLast[10] = {0};
  for (int p = 0; p < 14; ++p) {
    PassK& P = C.pass[p];
    const int pg = p & 1, wbase = pg * 7;

    unsigned pm[7];
    for (int i = 0; i < 7; ++i) pm[i] = phi_full((unsigned)allmask[p][i], acol) & 15u;
    int ca = 0, cb = 1, cc2 = 2, best = -1;
    for (int x = 0; x < 7; ++x)
      for (int y = x + 1; y < 7; ++y)
        for (int z = y + 1; z < 7; ++z) {
          int r = rank3n(pm[x], pm[y], pm[z]);
          if (r > best) { best = r; ca = x; cb = y; cc2 = z; }
        }

    unsigned cmL[3] = {allmask[p][ca], allmask[p][cb], allmask[p][cc2]};
    unsigned srowAll[7];
    srowAll[4] = allrow[p][ca]; srowAll[5] = allrow[p][cb]; srowAll[6] = allrow[p][cc2];
    P.widx[4] = (u16)(wbase + ca); P.widx[5] = (u16)(wbase + cb);
    P.widx[6] = (u16)(wbase + cc2);
    u16 mk[4]; int ii = 0;
    for (int i = 0; i < 7; ++i)
      if (i != ca && i != cb && i != cc2) {
        mk[ii] = allmask[p][i]; srowAll[ii] = allrow[p][i];
        P.widx[ii] = (u16)(wbase + i); ++ii;
      }
    if (p == 13) for (int i = 0; i < 4; ++i) mkLast[i] = mk[i];

    unsigned red[14] = {0};
    auto tryAdd = [&](unsigned x) -> bool {
      while (x) {
        int h = 31 - __builtin_clz(x);
        if (!red[h]) { red[h] = x; return true; }
        x ^= red[h];
      }
      return false;
    };
    for (int i = 0; i < 7; ++i) tryAdd((unsigned)allmask[p][i]);

    unsigned nb[4] = {0, 0, 0, 0};
    for (int i = 0; i < 3; ++i) {
      unsigned u = pm[i == 0 ? ca : (i == 1 ? cb : cc2)];
      for (int bit = 3; bit >= 0; --bit)
        if (((u >> bit) & 1u) && nb[bit]) u ^= nb[bit];
      if (u) nb[31 - __builtin_clz(u)] = u;
    }
    unsigned uTarget = 0;
    for (unsigned v = 1; v < 16; ++v) {
      unsigned r = v;
      for (int bit = 3; bit >= 0; --bit)
        if (((r >> bit) & 1u) && nb[bit]) r ^= nb[bit];
      if (r) { uTarget = v; break; }
    }
    unsigned scol[7];
    {
      bool ok = false;
      for (unsigned h = 0; h < 256u && !ok; ++h) {
        unsigned d4 = 0;
        for (int j = 0; j < 8; ++j) if ((h >> j) & 1u) d4 ^= acol[j];
        unsigned v = ((uTarget ^ d4) & 15u) | (h << 6);
        if (v && tryAdd(v)) { scol[0] = v; ok = true; }
      }
      for (unsigned cand = 1; cand < 16384u && !ok; ++cand)
        if (tryAdd(cand)) { scol[0] = cand; ok = true; }
    }
    for (int i2 = 1; i2 < 7; ++i2) {
      bool ok = false;
      for (unsigned h = 1; h < 256u && !ok; ++h)
        if (tryAdd(h << 6)) { scol[i2] = h << 6; ok = true; }
      for (unsigned cand = 1; cand < 16384u && !ok; ++cand)
        if (tryAdd(cand)) { scol[i2] = cand; ok = true; }
    }

    unsigned lcol[10] = {cmL[0], cmL[1], scol[0], cmL[2],
                         scol[1], scol[2], scol[3], scol[4], scol[5], scol[6]};
    for (int b = 0; b < 10; ++b) P.pcol[b] = (u16)phi_full(lcol[b], acol);
    if (p == 13) for (int b = 0; b < 10; ++b) lcolLast[b] = lcol[b];

    for (int i = 0; i < 7; ++i) {
      unsigned m = 0;
      for (int b = 0; b < 10; ++b)
        m |= (unsigned)par(srowAll[i] & lcol[b]) << b;
      P.sm[i] = (u16)m;
    }
    for (int e = 0; e < 16; ++e) {
      unsigned v = 0;
      for (int i = 0; i < 4; ++i)
        if ((e >> i) & 1) v ^= (unsigned)mk[i];
      P.pxm[e] = (u16)phi_full(v, acol);
    }
  }

  for (int w = 0; w < NQ; ++w) {
    unsigned zf = 0;
    for (int i = 0; i < 4; ++i)
      zf |= (unsigned)par((unsigned)zrow[w] & (unsigned)mkLast[i]) << i;
    C.zfreq[w] = (u16)zf;
    unsigned m = 0;
    for (int b = 0; b < 10; ++b)
      m |= (unsigned)par((unsigned)zrow[w] & lcolLast[b]) << b;
    C.zm[w] = (u16)m;
  }
  for (int e = 0; e < 16; ++e) {
    unsigned d4 = 0;
    for (int k = 0; k < 4; ++k)
      if ((e >> k) & 1) d4 ^= acol[4 + k];
    C.de[e] = (u16)d4;
  }
  for (int j = 0; j < 4; ++j) C.dcolw[j] = (u16)acol[j];

  // ---- workspace layout ----
  // bytes [0,4096): trig (tt/tq/S2 as floats)
  // bytes [8192, 8192+448K): tg/rep table (14*1024 recs * 32B)
  // albe at 466944 (table mode) or 4096 (no table)
  const size_t needT = 4096;
  const size_t tblOff = 8192;
  const size_t tblBytes = (size_t)NPASS * 1024 * 32;
  const size_t needTbl = tblOff + tblBytes;           // 466944
  const bool useT = ws_size >= needT;
  const bool useTbl = ws_size >= needTbl;
  const size_t albeOff = useTbl ? needTbl : 4096;
  const size_t needA = albeOff + (size_t)batch * NQ * sizeof(float4);
  const bool useA = useT && ws_size >= needA;

  float* wsf = (float*)d_ws;
  float2* tt = (float2*)wsf;
  float2* tq = (float2*)(wsf + 256);
  float* s2p = wsf + 512;
  float4* tbl = (float4*)((char*)d_ws + tblOff);
  float4* albe = (float4*)((char*)d_ws + albeOff);

  if (useT) {
    const int nAlbe = useA ? batch * NQ : 0;
    int nwork = DEPTH * NQ;
    if (useTbl && NPASS * 1024 > nwork) nwork = NPASS * 1024;
    if (useA && nAlbe > nwork) nwork = nAlbe;
    prep_kernel<<<(nwork + 255) / 256, 256, 0, stream>>>(
        inp, theta, wsf, useTbl ? tbl : nullptr, useA ? albe : nullptr,
        nAlbe, C);
    if (useTbl) {
      qsim_tbl_kernel<<<batch, TPB, 0, stream>>>(inp, theta, out, tt, s2p,
                                                 albe, useA ? 1 : 0, tbl, C);
    } else {
      qsim_kernel<true><<<batch, TPB, 0, stream>>>(inp, theta, out, tt, tq,
                                                   s2p, albe, useA ? 1 : 0, C);
    }
  } else {
    qsim_kernel<false><<<batch, TPB, 0, stream>>>(inp, theta, out, nullptr,
                                                  nullptr, nullptr, nullptr, 0, C);
  }
}

// Round 15
// 163.356 us; speedup vs baseline: 1.1837x; 1.0809x over previous
//
#include <hip/hip_runtime.h>

typedef unsigned short u16;
typedef float f2 __attribute__((ext_vector_type(2)));

#define NQ 14
#define NSTATE (1 << NQ)   // 16384
#define DEPTH 8
#define TPB 1024
#define NPASS 14

// ---------- host-side constants passed by value ----------
struct PassK {
  u16 pcol[10];    // PHYSICAL rep columns for t bits 0..9
  u16 sm[7];       // sign masks over t; slots 0..3 in-reg, 4..6 cross
  u16 widx[7];     // within-layer theta index per slot (0..13)
  u16 pxm[16];     // PHYSICAL xm (XOR combos of in-reg masks, mapped by Phi)
};

struct SimConsts {
  PassK pass[NPASS];  // layers 1..7 x two 7-wire passes
  u16 zm[14];      // measurement sign masks over t (last-pass basis)
  u16 zfreq[14];   // 4-bit WHT frequency per wire (last-pass mask basis)
  u16 de[16];      // init-write address delta per e (Phi correction)
  u16 dcolw[4];    // init-write delta columns for t bits 6..9
};

// ---------- device ----------
__device__ __forceinline__ f2 cmulv(f2 a, f2 b) {
  f2 r;
  r.x = a.x * b.x - a.y * b.y;
  r.y = a.x * b.y + a.y * b.x;
  return r;
}

// Packed in-register butterfly (fallback path): xn = x - t*y ; yn = y + t*x.
__device__ __forceinline__ void bfly_pk(f2& x, f2& y, f2 tp, f2 tn) {
  f2 xn, yn;
  asm("v_pk_fma_f32 %0, %4, %3, %2\n\t"   // xn = tn*y + x
      "v_pk_fma_f32 %1, %5, %2, %3"       // yn = tp*x + y
      : "=&v"(xn), "=&v"(yn)
      : "v"(x), "v"(y), "v"(tn), "v"(tp));
  x = xn; y = yn;
}

// Fused cross-wire butterfly: a += tg * partner(a), partner via DPP on src0.
// s_nop 1 covers the 2-wait-state VALU-write -> DPP-read hazard.
__device__ __forceinline__ void xfmac_l1(f2& v, float tg) {   // partner lane^1
  float x = v.x, y = v.y;
  asm("s_nop 1\n\t"
      "v_fmac_f32_dpp %0, %0, %2 quad_perm:[1,0,3,2] row_mask:0xf bank_mask:0xf\n\t"
      "v_fmac_f32_dpp %1, %1, %2 quad_perm:[1,0,3,2] row_mask:0xf bank_mask:0xf"
      : "+v"(x), "+v"(y) : "v"(tg));
  v.x = x; v.y = y;
}
__device__ __forceinline__ void xfmac_l2(f2& v, float tg) {   // partner lane^2
  float x = v.x, y = v.y;
  asm("s_nop 1\n\t"
      "v_fmac_f32_dpp %0, %0, %2 quad_perm:[2,3,0,1] row_mask:0xf bank_mask:0xf\n\t"
      "v_fmac_f32_dpp %1, %1, %2 quad_perm:[2,3,0,1] row_mask:0xf bank_mask:0xf"
      : "+v"(x), "+v"(y) : "v"(tg));
  v.x = x; v.y = y;
}
__device__ __forceinline__ void xfmac_l8(f2& v, float tg) {   // partner lane^8
  float x = v.x, y = v.y;
  asm("s_nop 1\n\t"
      "v_fmac_f32_dpp %0, %0, %2 row_ror:8 row_mask:0xf bank_mask:0xf\n\t"
      "v_fmac_f32_dpp %1, %1, %2 row_ror:8 row_mask:0xf bank_mask:0xf"
      : "+v"(x), "+v"(y) : "v"(tg));
  v.x = x; v.y = y;
}

// ---- TABLE-mode pass: tg[7] + rep come from the precomputed record.
template <bool WRITE>
__device__ __forceinline__ void ry7t(f2* st, const u16* pxm,
                                     float4 v0, float4 v1, f2* a) {
  const unsigned rep = __float_as_uint(v1.w);
  const unsigned base = rep << 3;
  unsigned ad[16];
  #pragma unroll
  for (int e = 0; e < 16; ++e)
    ad[e] = base ^ (((unsigned)pxm[e]) << 3);   // pxm<<3 uniform (SGPR)

  #pragma unroll
  for (int e = 0; e < 16; ++e) a[e] = *(const f2*)((const char*)st + ad[e]);

  // cross slot 4: partner = lane^1
  #pragma unroll
  for (int e = 0; e < 16; ++e) xfmac_l1(a[e], v1.x);
  // 4 in-register wires (tangent butterflies, plain C)
  float tgr[4] = {v0.x, v0.y, v0.z, v0.w};
  #pragma unroll
  for (int i = 0; i < 4; ++i) {
    const float ti = tgr[i];
    #pragma unroll
    for (int e = 0; e < 16; ++e) {
      if (!(e & (1 << i))) {
        f2 xe = a[e], ye = a[e | (1 << i)];
        a[e]            = xe - ti * ye;
        a[e | (1 << i)] = ye + ti * xe;
      }
    }
  }
  // cross slot 5: partner = lane^2
  #pragma unroll
  for (int e = 0; e < 16; ++e) xfmac_l2(a[e], v1.y);
  // cross slot 6: partner = lane^8
  #pragma unroll
  for (int e = 0; e < 16; ++e) xfmac_l8(a[e], v1.z);

  if constexpr (WRITE) {
    #pragma unroll
    for (int e = 0; e < 16; ++e) *(f2*)((char*)st + ad[e]) = a[e];
  }
}

// ---- FALLBACK pass (no table): R13's verified path.
template <bool USE_WS, bool WRITE>
__device__ __forceinline__ void ry7x(f2* st, const PassK& P, const float* th,
                                     const float2* tqd, int t, f2* a) {
  const unsigned wv = __builtin_amdgcn_readfirstlane(((unsigned)t) >> 6);
  unsigned rep = 0;
  #pragma unroll
  for (int j = 0; j < 4; ++j)
    rep ^= ((wv >> j) & 1u) ? (unsigned)P.pcol[6 + j] : 0u;
  #pragma unroll
  for (int b = 0; b < 6; ++b)
    rep ^= ((t >> b) & 1u) ? (unsigned)P.pcol[b] : 0u;

  float tv[7];
  #pragma unroll
  for (int i = 0; i < 7; ++i) {
    if constexpr (USE_WS) {
      tv[i] = tqd[P.widx[i]].x;
    } else {
      float ss, cc; __sincosf(0.5f * th[P.widx[i]], &ss, &cc);
      float ca = (fabsf(cc) < 1e-20f) ? copysignf(1e-20f, cc) : cc;
      tv[i] = ss / ca;
    }
  }
  float tg[7];
  #pragma unroll
  for (int i = 0; i < 4; ++i)
    tg[i] = (__popc((unsigned)P.sm[i] & (unsigned)t) & 1) ? -tv[i] : tv[i];
  #pragma unroll
  for (int i = 4; i < 7; ++i)
    tg[i] = (__popc((unsigned)P.sm[i] & (unsigned)t) & 1) ? tv[i] : -tv[i];

  const unsigned base = rep << 3;
  unsigned ad[16];
  #pragma unroll
  for (int e = 0; e < 16; ++e)
    ad[e] = base ^ (((unsigned)P.pxm[e]) << 3);

  #pragma unroll
  for (int e = 0; e < 16; ++e) a[e] = *(const f2*)((const char*)st + ad[e]);

  #pragma unroll
  for (int e = 0; e < 16; ++e) xfmac_l1(a[e], tg[4]);
  #pragma unroll
  for (int i = 0; i < 4; ++i) {
    f2 tp, tn;
    tp.x = tg[i]; tp.y = tg[i];
    tn.x = -tg[i]; tn.y = -tg[i];
    #pragma unroll
    for (int e = 0; e < 16; ++e) {
      if (!(e & (1 << i))) bfly_pk(a[e], a[e | (1 << i)], tp, tn);
    }
  }
  #pragma unroll
  for (int e = 0; e < 16; ++e) xfmac_l2(a[e], tg[5]);
  #pragma unroll
  for (int e = 0; e < 16; ++e) xfmac_l8(a[e], tg[6]);

  if constexpr (WRITE) {
    #pragma unroll
    for (int e = 0; e < 16; ++e) *(f2*)((char*)st + ad[e]) = a[e];
  }
}

// ---- shared init + measurement bodies ----
__device__ __forceinline__ void init_state(f2* st, f2* a, const f2* A,
                                           const f2* B, int t,
                                           const SimConsts& C) {
  f2 rhi; rhi.x = 1.f; rhi.y = 0.f;
  #pragma unroll
  for (int b = 0; b < 10; ++b) {           // p bit b <- t bit b, wire 13-b
    const int w = 13 - b;
    f2 f = ((t >> b) & 1) ? B[w] : A[w];
    rhi = cmulv(rhi, f);
  }
  a[0] = rhi;
  #pragma unroll
  for (int k = 0; k < 4; ++k) {            // e bit k <-> p bit 10+k <-> wire 3-k
    const int w = 3 - k;
    const int sz = 1 << k;
    #pragma unroll
    for (int j = 0; j < 8; ++j) {
      if (j < sz) {
        f2 v = a[j];
        a[j]      = cmulv(v, A[w]);
        a[j + sz] = cmulv(v, B[w]);
      }
    }
  }
  unsigned dw = 0;
  #pragma unroll
  for (int j = 0; j < 4; ++j)
    dw ^= ((t >> (6 + j)) & 1u) ? (unsigned)C.dcolw[j] : 0u;
  #pragma unroll
  for (int e = 0; e < 16; ++e)
    st[(((unsigned)e << 10) | (unsigned)t) ^ (unsigned)C.de[e] ^ dw] = a[e];
}

// Measurement: per-thread |amp|^2 + 4-bit WHT, write pvhat once, then
// WAVE-PER-WIRE reduction: wave w sums +-pvhat[zf_w][t] over all 1024 t
// (lane L handles t=(k<<6)|L, per-k reads are 256B-contiguous ->
// conflict-free), one 6-step wave reduce, lane 0 stores out[w] directly.
__device__ __forceinline__ void measure_out(f2* st, f2* a, int s, int t,
                                            float s2v, float* out,
                                            const SimConsts& C) {
  float pv[16];
  #pragma unroll
  for (int e = 0; e < 16; ++e) pv[e] = a[e].x * a[e].x + a[e].y * a[e].y;
  #pragma unroll
  for (int s4 = 0; s4 < 4; ++s4) {
    const int step = 1 << s4;
    #pragma unroll
    for (int e = 0; e < 16; ++e) {
      if (!(e & step)) {
        float x = pv[e], y = pv[e | step];
        pv[e] = x + y; pv[e | step] = x - y;
      }
    }
  }
  float* stf = (float*)st;
  #pragma unroll
  for (int e = 0; e < 16; ++e) stf[(e << 10) | t] = pv[e];
  __syncthreads();

  const int wv = t >> 6;     // wave id 0..15
  const int ln = t & 63;
  if (wv < NQ) {
    const unsigned zf = (unsigned)C.zfreq[wv];
    const unsigned zm = (unsigned)C.zm[wv];
    const float* src = stf + (zf << 10);
    float accv = 0.f;
    #pragma unroll
    for (int k = 0; k < 16; ++k) {
      const unsigned tt = ((unsigned)k << 6) | (unsigned)ln;
      float v = src[tt];
      accv += (__popc(zm & tt) & 1) ? -v : v;
    }
    #pragma unroll
    for (int off = 32; off > 0; off >>= 1)
      accv += __shfl_xor(accv, off, 64);
    if (ln == 0) out[s * NQ + wv] = accv * s2v;
  }
}

// ---- TABLE-mode main kernel ----
__global__ __launch_bounds__(TPB, 1) void qsim_tbl_kernel(
    const float* __restrict__ inp, const float* __restrict__ theta,
    float* __restrict__ out, const float2* __restrict__ tt,
    const float* __restrict__ s2p, const float4* __restrict__ albe,
    int use_albe, const float4* __restrict__ tbl, SimConsts C) {
  __shared__ f2 st[NSTATE];   // 128 KiB
  const int s = blockIdx.x;
  const int t = threadIdx.x;

  // prefetch pass-0 record early (hides under init)
  float4 c0 = tbl[(size_t)t * 2];
  float4 c1 = tbl[(size_t)t * 2 + 1];

  f2 A[NQ], B[NQ];
  if (use_albe) {
    #pragma unroll
    for (int w = 0; w < NQ; ++w) {
      float4 v = albe[s * NQ + w];       // uniform -> s_load_dwordx4
      A[w].x = v.x; A[w].y = v.y;
      B[w].x = v.z; B[w].y = v.w;
    }
  } else {
    #pragma unroll
    for (int w = 0; w < NQ; ++w) {
      float sx, cx; __sincosf(0.5f * inp[s * NQ + w], &sx, &cx);
      float2 tvv = tt[w];
      A[w].x = tvv.x * cx; A[w].y = tvv.y * sx;
      B[w].x = tvv.y * cx; B[w].y = -tvv.x * sx;
    }
  }

  f2 a[16];
  init_state(st, a, A, B, t, C);
  __syncthreads();

  // passes 0..12 (write), software-pipelined table loads
  #pragma unroll 1
  for (int p = 0; p < NPASS - 1; ++p) {
    float4 n0, n1;
    {
      const float4* nb = tbl + ((size_t)(p + 1) * 1024 + (size_t)t) * 2;
      n0 = nb[0]; n1 = nb[1];
    }
    ry7t<true>(st, C.pass[p].pxm, c0, c1, a);
    __syncthreads();
    c0 = n0; c1 = n1;
  }
  // pass 13: keep results in registers, fuse measurement
  ry7t<false>(st, C.pass[NPASS - 1].pxm, c0, c1, a);
  __syncthreads();

  measure_out(st, a, s, t, *s2p, out, C);
}

// ---- FALLBACK main kernel ----
template <bool USE_WS>
__global__ __launch_bounds__(TPB, 1) void qsim_kernel(
    const float* __restrict__ inp, const float* __restrict__ theta,
    float* __restrict__ out, const float2* __restrict__ tt,
    const float2* __restrict__ tq, const float* __restrict__ s2p,
    const float4* __restrict__ albe, int use_albe, SimConsts C) {
  __shared__ f2 st[NSTATE];
  const int s = blockIdx.x;
  const int t = threadIdx.x;

  f2 A[NQ], B[NQ];
  if constexpr (USE_WS) {
    if (use_albe) {
      #pragma unroll
      for (int w = 0; w < NQ; ++w) {
        float4 v = albe[s * NQ + w];
        A[w].x = v.x; A[w].y = v.y;
        B[w].x = v.z; B[w].y = v.w;
      }
    } else {
      #pragma unroll
      for (int w = 0; w < NQ; ++w) {
        float sx, cx; __sincosf(0.5f * inp[s * NQ + w], &sx, &cx);
        float2 tvv = tt[w];
        A[w].x = tvv.x * cx; A[w].y = tvv.y * sx;
        B[w].x = tvv.y * cx; B[w].y = -tvv.x * sx;
      }
    }
  } else {
    #pragma unroll
    for (int w = 0; w < NQ; ++w) {
      float sx, cx; __sincosf(0.5f * inp[s * NQ + w], &sx, &cx);
      float stt, ctt; __sincosf(0.5f * theta[w], &stt, &ctt);
      A[w].x = ctt * cx; A[w].y = stt * sx;
      B[w].x = stt * cx; B[w].y = -ctt * sx;
    }
  }

  f2 a[16];
  init_state(st, a, A, B, t, C);
  __syncthreads();

  #pragma unroll 1
  for (int d = 1; d <= 6; ++d) {
    const float* th = theta + d * NQ;
    const float2* tqd = USE_WS ? (tq + d * NQ) : nullptr;
    ry7x<USE_WS, true>(st, C.pass[(d - 1) * 2 + 0], th, tqd, t, a);
    __syncthreads();
    ry7x<USE_WS, true>(st, C.pass[(d - 1) * 2 + 1], th, tqd, t, a);
    __syncthreads();
  }
  {
    const float* th = theta + 7 * NQ;
    const float2* tqd = USE_WS ? (tq + 7 * NQ) : nullptr;
    ry7x<USE_WS, true>(st, C.pass[12], th, tqd, t, a);
    __syncthreads();
    ry7x<USE_WS, false>(st, C.pass[13], th, tqd, t, a);
  }
  __syncthreads();

  float s2v;
  if constexpr (USE_WS) {
    s2v = *s2p;
  } else {
    double pr = 1.0;
    for (int j = NQ; j < DEPTH * NQ; ++j) {
      float ss, cc; sincosf(0.5f * theta[j], &ss, &cc);
      pr *= (double)cc * (double)cc;
    }
    s2v = (float)pr;
  }
  measure_out(st, a, s, t, s2v, out, C);
}

// ---------- prep: trig tables + deferred scale + tg/rep table ----------
__global__ void prep_kernel(const float* __restrict__ inp,
                            const float* __restrict__ theta,
                            float* __restrict__ ws, float4* __restrict__ tbl,
                            float4* __restrict__ albe, int nAlbe, SimConsts C) {
  const int i = blockIdx.x * 256 + threadIdx.x;
  float2* tt = (float2*)ws;
  float2* tq = (float2*)(ws + 256);
  if (i < DEPTH * NQ) {
    float ss, cc; sincosf(0.5f * theta[i], &ss, &cc);
    tt[i] = make_float2(cc, ss);
    float ca = (fabsf(cc) < 1e-20f) ? copysignf(1e-20f, cc) : cc;
    tq[i] = make_float2(ss / ca, ca);
  }
  if (i == 0) {
    double pr = 1.0;
    for (int j = NQ; j < DEPTH * NQ; ++j) {
      double cc = cos(0.5 * (double)theta[j]);
      pr *= cc * cc;
    }
    ws[512] = (float)pr;
  }
  if (tbl != nullptr && i < NPASS * 1024) {
    const int p = i >> 10, t = i & 1023;
    const PassK& P = C.pass[p];
    const int d = (p >> 1) + 1;
    float tg[7];
    #pragma unroll
    for (int k = 0; k < 7; ++k) {
      float ss, cc; sincosf(0.5f * theta[d * NQ + P.widx[k]], &ss, &cc);
      float ca = (fabsf(cc) < 1e-20f) ? copysignf(1e-20f, cc) : cc;
      float tv = ss / ca;
      int sg = __popc((unsigned)P.sm[k] & (unsigned)t) & 1;
      tg[k] = (k < 4) ? (sg ? -tv : tv) : (sg ? tv : -tv);
    }
    unsigned rep = 0;
    #pragma unroll
    for (int b = 0; b < 10; ++b)
      rep ^= ((t >> b) & 1u) ? (unsigned)P.pcol[b] : 0u;
    tbl[(size_t)i * 2]     = make_float4(tg[0], tg[1], tg[2], tg[3]);
    tbl[(size_t)i * 2 + 1] = make_float4(tg[4], tg[5], tg[6],
                                         __uint_as_float(rep));
  }
  if (albe != nullptr && i < nAlbe) {
    const int w = i % NQ;
    float sx, cx; sincosf(0.5f * inp[i], &sx, &cx);
    float stt, ctt; sincosf(0.5f * theta[w], &stt, &ctt);
    albe[i] = make_float4(ctt * cx, stt * sx, stt * cx, -ctt * sx);
  }
}

// ---------- host: GF(2) linear algebra for the CNOT-ring permutation ----------
static inline unsigned ffwd(unsigned x) {
  unsigned t = x;
  t ^= t >> 1; t ^= t >> 2; t ^= t >> 4; t ^= t >> 8;
  unsigned y = t & 0x1FFFu;
  y |= (((t >> 13) ^ t) & 1u) << 13;
  return y;
}
static inline unsigned finv(unsigned y) {
  unsigned x = 0;
  for (int j = 0; j <= 11; ++j) x |= (((y >> j) ^ (y >> (j + 1))) & 1u) << j;
  x |= (((y >> 12) ^ (y >> 13) ^ y) & 1u) << 12;
  x |= (((y >> 13) ^ y) & 1u) << 13;
  return x;
}
static inline int rank3n(unsigned a, unsigned b, unsigned c) {
  unsigned bas[4] = {0, 0, 0, 0};
  unsigned vv[3] = {a & 15u, b & 15u, c & 15u};
  int r = 0;
  for (int i = 0; i < 3; ++i) {
    unsigned u = vv[i];
    for (int bit = 3; bit >= 0; --bit)
      if (((u >> bit) & 1u) && bas[bit]) u ^= bas[bit];
    if (u) { bas[31 - __builtin_clz(u)] = u; ++r; }
  }
  return r;
}
static inline unsigned phi_full(unsigned m, const unsigned* ac) {
  unsigned d = 0;
  for (int j = 0; j < 8; ++j)
    if ((m >> (6 + j)) & 1u) d ^= ac[j];
  return m ^ d;
}
static inline int par(unsigned x) { return __builtin_popcount(x) & 1; }

static int scoreA(const unsigned* ac, const u16 am[14][7], int bail) {
  int s = 0;
  for (int p = 0; p < 14; ++p) {
    unsigned pm[7];
    for (int i = 0; i < 7; ++i) pm[i] = phi_full((unsigned)am[p][i], ac) & 15u;
    int best = 0;
    for (int x = 0; x < 7 && best < 3; ++x)
      for (int y = x + 1; y < 7 && best < 3; ++y)
        for (int z = y + 1; z < 7 && best < 3; ++z) {
          int r = rank3n(pm[x], pm[y], pm[z]);
          if (r > best) best = r;
        }
    if (best < 3) s += 3 - best;
    if (s >= bail) return s;
  }
  return s;
}

extern "C" void kernel_launch(void* const* d_in, const int* in_sizes, int n_in,
                              void* d_out, int out_size, void* d_ws, size_t ws_size,
                              hipStream_t stream) {
  const float* inp = (const float*)d_in[0];
  const float* theta = (const float*)d_in[1];
  float* out = (float*)d_out;
  const int batch = in_sizes[0] / NQ;

  // ---- collect per-pass wire masks (K cols) and sign rows (L rows)
  u16 Lc[NQ], Kc[NQ];
  u16 allmask[14][7]; unsigned allrow[14][7];
  u16 zrow[NQ];
  for (int j = 0; j < NQ; ++j) { Lc[j] = (u16)(1u << j); Kc[j] = (u16)(1u << j); }
  for (int d = 1; d <= 8; ++d) {
    u16 nL[NQ], nK[NQ];
    for (int j = 0; j < NQ; ++j) nL[j] = (u16)ffwd((unsigned)Lc[j]);
    for (int j = 0; j < NQ; ++j) {
      unsigned fj = finv(1u << j);
      unsigned v = 0;
      for (int b = 0; b < NQ; ++b) if ((fj >> b) & 1u) v ^= Kc[b];
      nK[j] = (u16)v;
    }
    for (int j = 0; j < NQ; ++j) { Lc[j] = nL[j]; Kc[j] = nK[j]; }

    if (d <= 7) {
      for (int pg = 0; pg < 2; ++pg) {
        const int p = (d - 1) * 2 + pg;
        const int wbase = pg * 7;
        for (int i = 0; i < 7; ++i) {
          const int bit = 13 - (wbase + i);
          allmask[p][i] = Kc[bit];
          unsigned r = 0;
          for (int j = 0; j < NQ; ++j) r |= ((unsigned)(Lc[j] >> bit) & 1u) << j;
          allrow[p][i] = r;
        }
      }
    } else {
      for (int w = 0; w < NQ; ++w) {
        const int bit = 13 - w;
        unsigned r = 0;
        for (int j = 0; j < NQ; ++j) r |= ((unsigned)(Lc[j] >> bit) & 1u) << j;
        zrow[w] = (u16)r;
      }
    }
  }

  // ---- search layout map A (8 cols -> low4) so every pass has a rank-3 triple
  unsigned acol[8] = {0, 0, 0, 0, 0, 0, 0, 0};
  int bestSc = scoreA(acol, allmask, 1 << 30);
  if (bestSc > 0) {
    unsigned long long seed = 88172645463325252ULL;
    for (int it = 0; it < 20000 && bestSc > 0; ++it) {
      unsigned cand[8];
      for (int j = 0; j < 8; ++j) {
        seed ^= seed << 13; seed ^= seed >> 7; seed ^= seed << 17;
        cand[j] = (unsigned)(seed & 15u);
      }
      int sc = scoreA(cand, allmask, bestSc);
      if (sc < bestSc) {
        bestSc = sc;
        for (int j = 0; j < 8; ++j) acol[j] = cand[j];
      }
    }
  }

  // ---- build pass constants
  SimConsts C;
  u16 mkLast[4] = {0, 0, 0, 0};
  unsigned lcolLast[10] = {0};
  for (int p = 0; p < 14; ++p) {
    PassK& P = C.pass[p];
    const int pg = p & 1, wbase = pg * 7;

    unsigned pm[7];
    for (int i = 0; i < 7; ++i) pm[i] = phi_full((unsigned)allmask[p][i], acol) & 15u;
    int ca = 0, cb = 1, cc2 = 2, best = -1;
    for (int x = 0; x < 7; ++x)
      for (int y = x + 1; y < 7; ++y)
        for (int z = y + 1; z < 7; ++z) {
          int r = rank3n(pm[x], pm[y], pm[z]);
          if (r > best) { best = r; ca = x; cb = y; cc2 = z; }
        }

    unsigned cmL[3] = {allmask[p][ca], allmask[p][cb], allmask[p][cc2]};
    unsigned srowAll[7];
    srowAll[4] = allrow[p][ca]; srowAll[5] = allrow[p][cb]; srowAll[6] = allrow[p][cc2];
    P.widx[4] = (u16)(wbase + ca); P.widx[5] = (u16)(wbase + cb);
    P.widx[6] = (u16)(wbase + cc2);
    u16 mk[4]; int ii = 0;
    for (int i = 0; i < 7; ++i)
      if (i != ca && i != cb && i != cc2) {
        mk[ii] = allmask[p][i]; srowAll[ii] = allrow[p][i];
        P.widx[ii] = (u16)(wbase + i); ++ii;
      }
    if (p == 13) for (int i = 0; i < 4; ++i) mkLast[i] = mk[i];

    unsigned red[14] = {0};
    auto tryAdd = [&](unsigned x) -> bool {
      while (x) {
        int h = 31 - __builtin_clz(x);
        if (!red[h]) { red[h] = x; return true; }
        x ^= red[h];
      }
      return false;
    };
    for (int i = 0; i < 7; ++i) tryAdd((unsigned)allmask[p][i]);

    unsigned nb[4] = {0, 0, 0, 0};
    for (int i = 0; i < 3; ++i) {
      unsigned u = pm[i == 0 ? ca : (i == 1 ? cb : cc2)];
      for (int bit = 3; bit >= 0; --bit)
        if (((u >> bit) & 1u) && nb[bit]) u ^= nb[bit];
      if (u) nb[31 - __builtin_clz(u)] = u;
    }
    unsigned uTarget = 0;
    for (unsigned v = 1; v < 16; ++v) {
      unsigned r = v;
      for (int bit = 3; bit >= 0; --bit)
        if (((r >> bit) & 1u) && nb[bit]) r ^= nb[bit];
      if (r) { uTarget = v; break; }
    }
    unsigned scol[7];
    {
      bool ok = false;
      for (unsigned h = 0; h < 256u && !ok; ++h) {
        unsigned d4 = 0;
        for (int j = 0; j < 8; ++j) if ((h >> j) & 1u) d4 ^= acol[j];
        unsigned v = ((uTarget ^ d4) & 15u) | (h << 6);
        if (v && tryAdd(v)) { scol[0] = v; ok = true; }
      }
      for (unsigned cand = 1; cand < 16384u && !ok; ++cand)
        if (tryAdd(cand)) { scol[0] = cand; ok = true; }
    }
    for (int i2 = 1; i2 < 7; ++i2) {
      bool ok = false;
      for (unsigned h = 1; h < 256u && !ok; ++h)
        if (tryAdd(h << 6)) { scol[i2] = h << 6; ok = true; }
      for (unsigned cand = 1; cand < 16384u && !ok; ++cand)
        if (tryAdd(cand)) { scol[i2] = cand; ok = true; }
    }

    unsigned lcol[10] = {cmL[0], cmL[1], scol[0], cmL[2],
                         scol[1], scol[2], scol[3], scol[4], scol[5], scol[6]};
    for (int b = 0; b < 10; ++b) P.pcol[b] = (u16)phi_full(lcol[b], acol);
    if (p == 13) for (int b = 0; b < 10; ++b) lcolLast[b] = lcol[b];

    for (int i = 0; i < 7; ++i) {
      unsigned m = 0;
      for (int b = 0; b < 10; ++b)
        m |= (unsigned)par(srowAll[i] & lcol[b]) << b;
      P.sm[i] = (u16)m;
    }
    for (int e = 0; e < 16; ++e) {
      unsigned v = 0;
      for (int i = 0; i < 4; ++i)
        if ((e >> i) & 1) v ^= (unsigned)mk[i];
      P.pxm[e] = (u16)phi_full(v, acol);
    }
  }

  for (int w = 0; w < NQ; ++w) {
    unsigned zf = 0;
    for (int i = 0; i < 4; ++i)
      zf |= (unsigned)par((unsigned)zrow[w] & (unsigned)mkLast[i]) << i;
    C.zfreq[w] = (u16)zf;
    unsigned m = 0;
    for (int b = 0; b < 10; ++b)
      m |= (unsigned)par((unsigned)zrow[w] & lcolLast[b]) << b;
    C.zm[w] = (u16)m;
  }
  for (int e = 0; e < 16; ++e) {
    unsigned d4 = 0;
    for (int k = 0; k < 4; ++k)
      if ((e >> k) & 1) d4 ^= acol[4 + k];
    C.de[e] = (u16)d4;
  }
  for (int j = 0; j < 4; ++j) C.dcolw[j] = (u16)acol[j];

  // ---- workspace layout ----
  const size_t needT = 4096;
  const size_t tblOff = 8192;
  const size_t tblBytes = (size_t)NPASS * 1024 * 32;
  const size_t needTbl = tblOff + tblBytes;           // 466944
  const bool useT = ws_size >= needT;
  const bool useTbl = ws_size >= needTbl;
  const size_t albeOff = useTbl ? needTbl : 4096;
  const size_t needA = albeOff + (size_t)batch * NQ * sizeof(float4);
  const bool useA = useT && ws_size >= needA;

  float* wsf = (float*)d_ws;
  float2* tt = (float2*)wsf;
  float2* tq = (float2*)(wsf + 256);
  float* s2p = wsf + 512;
  float4* tbl = (float4*)((char*)d_ws + tblOff);
  float4* albe = (float4*)((char*)d_ws + albeOff);

  if (useT) {
    const int nAlbe = useA ? batch * NQ : 0;
    int nwork = DEPTH * NQ;
    if (useTbl && NPASS * 1024 > nwork) nwork = NPASS * 1024;
    if (useA && nAlbe > nwork) nwork = nAlbe;
    prep_kernel<<<(nwork + 255) / 256, 256, 0, stream>>>(
        inp, theta, wsf, useTbl ? tbl : nullptr, useA ? albe : nullptr,
        nAlbe, C);
    if (useTbl) {
      qsim_tbl_kernel<<<batch, TPB, 0, stream>>>(inp, theta, out, tt, s2p,
                                                 albe, useA ? 1 : 0, tbl, C);
    } else {
      qsim_kernel<true><<<batch, TPB, 0, stream>>>(inp, theta, out, tt, tq,
                                                   s2p, albe, useA ? 1 : 0, C);
    }
  } else {
    qsim_kernel<false><<<batch, TPB, 0, stream>>>(inp, theta, out, nullptr,
                                                  nullptr, nullptr, nullptr, 0, C);
  }
}

// Round 16
// 150.483 us; speedup vs baseline: 1.2849x; 1.0855x over previous
//
#include <hip/hip_runtime.h>

typedef unsigned short u16;
typedef float f2 __attribute__((ext_vector_type(2)));

#define NQ 14
#define NSTATE (1 << NQ)   // 16384
#define DEPTH 8
#define TPB 1024
#define NPASS 14

// ---------- host-side constants passed by value ----------
struct PassK {
  u16 pcol[10];    // PHYSICAL rep columns for t bits 0..9
  u16 sm[7];       // sign masks over t; slots 0..3 in-reg, 4..6 cross
  u16 widx[7];     // within-layer theta index per slot (0..13)
  u16 pxm[16];     // PHYSICAL xm (XOR combos of in-reg masks, mapped by Phi)
};

struct SimConsts {
  PassK pass[NPASS];  // layers 1..7 x two 7-wire passes
  u16 zm[14];      // measurement sign masks over t (last-pass basis)
  u16 zfreq[14];   // 4-bit WHT frequency per wire (last-pass mask basis)
  u16 de[16];      // init-write address delta per e (Phi correction)
  u16 dcolw[4];    // init-write delta columns for t bits 6..9
};

// ---------- device ----------
__device__ __forceinline__ f2 cmulv(f2 a, f2 b) {
  f2 r;
  r.x = a.x * b.x - a.y * b.y;
  r.y = a.x * b.y + a.y * b.x;
  return r;
}

// 8-element fused cross-wire butterfly: a[e] += tg * partner(a[e]) for
// e=0..7, partner via DPP on src0. ONE leading s_nop 1 guards the
// VALU-write -> DPP-read hazard at block entry (whatever the scheduler
// placed before us); inside the block no instruction reads a register
// written by a predecessor, so no further nops are needed.
#define DEF_CROSS8(NAME, DPPSTR)                                            \
__device__ __forceinline__ void NAME(f2* a, float tg) {                     \
  float x0=a[0].x,y0=a[0].y,x1=a[1].x,y1=a[1].y,x2=a[2].x,y2=a[2].y,        \
        x3=a[3].x,y3=a[3].y,x4=a[4].x,y4=a[4].y,x5=a[5].x,y5=a[5].y,        \
        x6=a[6].x,y6=a[6].y,x7=a[7].x,y7=a[7].y;                            \
  asm("s_nop 1\n\t"                                                         \
      "v_fmac_f32_dpp %0, %0, %16 " DPPSTR "\n\t"                           \
      "v_fmac_f32_dpp %1, %1, %16 " DPPSTR "\n\t"                           \
      "v_fmac_f32_dpp %2, %2, %16 " DPPSTR "\n\t"                           \
      "v_fmac_f32_dpp %3, %3, %16 " DPPSTR "\n\t"                           \
      "v_fmac_f32_dpp %4, %4, %16 " DPPSTR "\n\t"                           \
      "v_fmac_f32_dpp %5, %5, %16 " DPPSTR "\n\t"                           \
      "v_fmac_f32_dpp %6, %6, %16 " DPPSTR "\n\t"                           \
      "v_fmac_f32_dpp %7, %7, %16 " DPPSTR "\n\t"                           \
      "v_fmac_f32_dpp %8, %8, %16 " DPPSTR "\n\t"                           \
      "v_fmac_f32_dpp %9, %9, %16 " DPPSTR "\n\t"                           \
      "v_fmac_f32_dpp %10, %10, %16 " DPPSTR "\n\t"                         \
      "v_fmac_f32_dpp %11, %11, %16 " DPPSTR "\n\t"                         \
      "v_fmac_f32_dpp %12, %12, %16 " DPPSTR "\n\t"                         \
      "v_fmac_f32_dpp %13, %13, %16 " DPPSTR "\n\t"                         \
      "v_fmac_f32_dpp %14, %14, %16 " DPPSTR "\n\t"                         \
      "v_fmac_f32_dpp %15, %15, %16 " DPPSTR                                \
      : "+v"(x0), "+v"(y0), "+v"(x1), "+v"(y1), "+v"(x2), "+v"(y2),         \
        "+v"(x3), "+v"(y3), "+v"(x4), "+v"(y4), "+v"(x5), "+v"(y5),         \
        "+v"(x6), "+v"(y6), "+v"(x7), "+v"(y7)                              \
      : "v"(tg));                                                           \
  a[0].x=x0; a[0].y=y0; a[1].x=x1; a[1].y=y1;                               \
  a[2].x=x2; a[2].y=y2; a[3].x=x3; a[3].y=y3;                               \
  a[4].x=x4; a[4].y=y4; a[5].x=x5; a[5].y=y5;                               \
  a[6].x=x6; a[6].y=y6; a[7].x=x7; a[7].y=y7;                               \
}

DEF_CROSS8(cross8_l1, "quad_perm:[1,0,3,2] row_mask:0xf bank_mask:0xf")
DEF_CROSS8(cross8_l2, "quad_perm:[2,3,0,1] row_mask:0xf bank_mask:0xf")
DEF_CROSS8(cross8_l8, "row_ror:8 row_mask:0xf bank_mask:0xf")

// ---- TABLE-mode pass: tg[7] + rep come from the precomputed record.
template <bool WRITE>
__device__ __forceinline__ void ry7t(f2* st, const u16* pxm,
                                     float4 v0, float4 v1, f2* a) {
  const unsigned rep = __float_as_uint(v1.w);
  const unsigned base = rep << 3;
  unsigned ad[16];
  #pragma unroll
  for (int e = 0; e < 16; ++e)
    ad[e] = base ^ (((unsigned)pxm[e]) << 3);   // pxm<<3 uniform (SGPR)

  #pragma unroll
  for (int e = 0; e < 16; ++e) a[e] = *(const f2*)((const char*)st + ad[e]);

  // cross slot 4: partner = lane^1
  cross8_l1(a, v1.x);
  cross8_l1(a + 8, v1.x);
  // 4 in-register wires (tangent butterflies, plain C)
  float tgr[4] = {v0.x, v0.y, v0.z, v0.w};
  #pragma unroll
  for (int i = 0; i < 4; ++i) {
    const float ti = tgr[i];
    #pragma unroll
    for (int e = 0; e < 16; ++e) {
      if (!(e & (1 << i))) {
        f2 xe = a[e], ye = a[e | (1 << i)];
        a[e]            = xe - ti * ye;
        a[e | (1 << i)] = ye + ti * xe;
      }
    }
  }
  // cross slot 5: partner = lane^2
  cross8_l2(a, v1.y);
  cross8_l2(a + 8, v1.y);
  // cross slot 6: partner = lane^8
  cross8_l8(a, v1.z);
  cross8_l8(a + 8, v1.z);

  if constexpr (WRITE) {
    #pragma unroll
    for (int e = 0; e < 16; ++e) *(f2*)((char*)st + ad[e]) = a[e];
  }
}

// ---- FALLBACK pass (no table): R13's verified path with cross8 blocks.
template <bool USE_WS, bool WRITE>
__device__ __forceinline__ void ry7x(f2* st, const PassK& P, const float* th,
                                     const float2* tqd, int t, f2* a) {
  const unsigned wv = __builtin_amdgcn_readfirstlane(((unsigned)t) >> 6);
  unsigned rep = 0;
  #pragma unroll
  for (int j = 0; j < 4; ++j)
    rep ^= ((wv >> j) & 1u) ? (unsigned)P.pcol[6 + j] : 0u;
  #pragma unroll
  for (int b = 0; b < 6; ++b)
    rep ^= ((t >> b) & 1u) ? (unsigned)P.pcol[b] : 0u;

  float tv[7];
  #pragma unroll
  for (int i = 0; i < 7; ++i) {
    if constexpr (USE_WS) {
      tv[i] = tqd[P.widx[i]].x;
    } else {
      float ss, cc; __sincosf(0.5f * th[P.widx[i]], &ss, &cc);
      float ca = (fabsf(cc) < 1e-20f) ? copysignf(1e-20f, cc) : cc;
      tv[i] = ss / ca;
    }
  }
  float tg[7];
  #pragma unroll
  for (int i = 0; i < 4; ++i)
    tg[i] = (__popc((unsigned)P.sm[i] & (unsigned)t) & 1) ? -tv[i] : tv[i];
  #pragma unroll
  for (int i = 4; i < 7; ++i)
    tg[i] = (__popc((unsigned)P.sm[i] & (unsigned)t) & 1) ? tv[i] : -tv[i];

  const unsigned base = rep << 3;
  unsigned ad[16];
  #pragma unroll
  for (int e = 0; e < 16; ++e)
    ad[e] = base ^ (((unsigned)P.pxm[e]) << 3);

  #pragma unroll
  for (int e = 0; e < 16; ++e) a[e] = *(const f2*)((const char*)st + ad[e]);

  cross8_l1(a, tg[4]);
  cross8_l1(a + 8, tg[4]);
  #pragma unroll
  for (int i = 0; i < 4; ++i) {
    const float ti = tg[i];
    #pragma unroll
    for (int e = 0; e < 16; ++e) {
      if (!(e & (1 << i))) {
        f2 xe = a[e], ye = a[e | (1 << i)];
        a[e]            = xe - ti * ye;
        a[e | (1 << i)] = ye + ti * xe;
      }
    }
  }
  cross8_l2(a, tg[5]);
  cross8_l2(a + 8, tg[5]);
  cross8_l8(a, tg[6]);
  cross8_l8(a + 8, tg[6]);

  if constexpr (WRITE) {
    #pragma unroll
    for (int e = 0; e < 16; ++e) *(f2*)((char*)st + ad[e]) = a[e];
  }
}

// ---- shared init + measurement bodies ----
__device__ __forceinline__ void init_state(f2* st, f2* a, const f2* A,
                                           const f2* B, int t,
                                           const SimConsts& C) {
  f2 rhi; rhi.x = 1.f; rhi.y = 0.f;
  #pragma unroll
  for (int b = 0; b < 10; ++b) {           // p bit b <- t bit b, wire 13-b
    const int w = 13 - b;
    f2 f = ((t >> b) & 1) ? B[w] : A[w];
    rhi = cmulv(rhi, f);
  }
  a[0] = rhi;
  #pragma unroll
  for (int k = 0; k < 4; ++k) {            // e bit k <-> p bit 10+k <-> wire 3-k
    const int w = 3 - k;
    const int sz = 1 << k;
    #pragma unroll
    for (int j = 0; j < 8; ++j) {
      if (j < sz) {
        f2 v = a[j];
        a[j]      = cmulv(v, A[w]);
        a[j + sz] = cmulv(v, B[w]);
      }
    }
  }
  unsigned dw = 0;
  #pragma unroll
  for (int j = 0; j < 4; ++j)
    dw ^= ((t >> (6 + j)) & 1u) ? (unsigned)C.dcolw[j] : 0u;
  #pragma unroll
  for (int e = 0; e < 16; ++e)
    st[(((unsigned)e << 10) | (unsigned)t) ^ (unsigned)C.de[e] ^ dw] = a[e];
}

// Measurement: per-thread |amp|^2 + 4-bit WHT, write pvhat once, then
// WAVE-PER-WIRE reduction (wave w handles wire w; per-k lane reads are
// 256B-contiguous -> conflict-free), one 6-step wave reduce, lane 0 stores.
__device__ __forceinline__ void measure_out(f2* st, f2* a, int s, int t,
                                            float s2v, float* out,
                                            const SimConsts& C) {
  float pv[16];
  #pragma unroll
  for (int e = 0; e < 16; ++e) pv[e] = a[e].x * a[e].x + a[e].y * a[e].y;
  #pragma unroll
  for (int s4 = 0; s4 < 4; ++s4) {
    const int step = 1 << s4;
    #pragma unroll
    for (int e = 0; e < 16; ++e) {
      if (!(e & step)) {
        float x = pv[e], y = pv[e | step];
        pv[e] = x + y; pv[e | step] = x - y;
      }
    }
  }
  float* stf = (float*)st;
  #pragma unroll
  for (int e = 0; e < 16; ++e) stf[(e << 10) | t] = pv[e];
  __syncthreads();

  const int wv = t >> 6;     // wave id 0..15
  const int ln = t & 63;
  if (wv < NQ) {
    const unsigned zf = (unsigned)C.zfreq[wv];
    const unsigned zm = (unsigned)C.zm[wv];
    const float* src = stf + (zf << 10);
    float accv = 0.f;
    #pragma unroll
    for (int k = 0; k < 16; ++k) {
      const unsigned tt = ((unsigned)k << 6) | (unsigned)ln;
      float v = src[tt];
      accv += (__popc(zm & tt) & 1) ? -v : v;
    }
    #pragma unroll
    for (int off = 32; off > 0; off >>= 1)
      accv += __shfl_xor(accv, off, 64);
    if (ln == 0) out[s * NQ + wv] = accv * s2v;
  }
}

// ---- TABLE-mode main kernel ----
__global__ __launch_bounds__(TPB, 1) void qsim_tbl_kernel(
    const float* __restrict__ inp, const float* __restrict__ theta,
    float* __restrict__ out, const float2* __restrict__ tt,
    const float* __restrict__ s2p, const float4* __restrict__ albe,
    int use_albe, const float4* __restrict__ tbl, SimConsts C) {
  __shared__ f2 st[NSTATE];   // 128 KiB
  const int s = blockIdx.x;
  const int t = threadIdx.x;

  // prefetch pass-0 record early (hides under init)
  float4 c0 = tbl[(size_t)t * 2];
  float4 c1 = tbl[(size_t)t * 2 + 1];

  f2 A[NQ], B[NQ];
  if (use_albe) {
    #pragma unroll
    for (int w = 0; w < NQ; ++w) {
      float4 v = albe[s * NQ + w];       // uniform -> s_load_dwordx4
      A[w].x = v.x; A[w].y = v.y;
      B[w].x = v.z; B[w].y = v.w;
    }
  } else {
    #pragma unroll
    for (int w = 0; w < NQ; ++w) {
      float sx, cx; __sincosf(0.5f * inp[s * NQ + w], &sx, &cx);
      float2 tvv = tt[w];
      A[w].x = tvv.x * cx; A[w].y = tvv.y * sx;
      B[w].x = tvv.y * cx; B[w].y = -tvv.x * sx;
    }
  }

  f2 a[16];
  init_state(st, a, A, B, t, C);
  __syncthreads();

  // passes 0..12 (write), software-pipelined table loads
  #pragma unroll 1
  for (int p = 0; p < NPASS - 1; ++p) {
    float4 n0, n1;
    {
      const float4* nb = tbl + ((size_t)(p + 1) * 1024 + (size_t)t) * 2;
      n0 = nb[0]; n1 = nb[1];
    }
    ry7t<true>(st, C.pass[p].pxm, c0, c1, a);
    __syncthreads();
    c0 = n0; c1 = n1;
  }
  // pass 13: keep results in registers, fuse measurement
  ry7t<false>(st, C.pass[NPASS - 1].pxm, c0, c1, a);
  __syncthreads();

  measure_out(st, a, s, t, *s2p, out, C);
}

// ---- FALLBACK main kernel ----
template <bool USE_WS>
__global__ __launch_bounds__(TPB, 1) void qsim_kernel(
    const float* __restrict__ inp, const float* __restrict__ theta,
    float* __restrict__ out, const float2* __restrict__ tt,
    const float2* __restrict__ tq, const float* __restrict__ s2p,
    const float4* __restrict__ albe, int use_albe, SimConsts C) {
  __shared__ f2 st[NSTATE];
  const int s = blockIdx.x;
  const int t = threadIdx.x;

  f2 A[NQ], B[NQ];
  if constexpr (USE_WS) {
    if (use_albe) {
      #pragma unroll
      for (int w = 0; w < NQ; ++w) {
        float4 v = albe[s * NQ + w];
        A[w].x = v.x; A[w].y = v.y;
        B[w].x = v.z; B[w].y = v.w;
      }
    } else {
      #pragma unroll
      for (int w = 0; w < NQ; ++w) {
        float sx, cx; __sincosf(0.5f * inp[s * NQ + w], &sx, &cx);
        float2 tvv = tt[w];
        A[w].x = tvv.x * cx; A[w].y = tvv.y * sx;
        B[w].x = tvv.y * cx; B[w].y = -tvv.x * sx;
      }
    }
  } else {
    #pragma unroll
    for (int w = 0; w < NQ; ++w) {
      float sx, cx; __sincosf(0.5f * inp[s * NQ + w], &sx, &cx);
      float stt, ctt; __sincosf(0.5f * theta[w], &stt, &ctt);
      A[w].x = ctt * cx; A[w].y = stt * sx;
      B[w].x = stt * cx; B[w].y = -ctt * sx;
    }
  }

  f2 a[16];
  init_state(st, a, A, B, t, C);
  __syncthreads();

  #pragma unroll 1
  for (int d = 1; d <= 6; ++d) {
    const float* th = theta + d * NQ;
    const float2* tqd = USE_WS ? (tq + d * NQ) : nullptr;
    ry7x<USE_WS, true>(st, C.pass[(d - 1) * 2 + 0], th, tqd, t, a);
    __syncthreads();
    ry7x<USE_WS, true>(st, C.pass[(d - 1) * 2 + 1], th, tqd, t, a);
    __syncthreads();
  }
  {
    const float* th = theta + 7 * NQ;
    const float2* tqd = USE_WS ? (tq + 7 * NQ) : nullptr;
    ry7x<USE_WS, true>(st, C.pass[12], th, tqd, t, a);
    __syncthreads();
    ry7x<USE_WS, false>(st, C.pass[13], th, tqd, t, a);
  }
  __syncthreads();

  float s2v;
  if constexpr (USE_WS) {
    s2v = *s2p;
  } else {
    double pr = 1.0;
    for (int j = NQ; j < DEPTH * NQ; ++j) {
      float ss, cc; sincosf(0.5f * theta[j], &ss, &cc);
      pr *= (double)cc * (double)cc;
    }
    s2v = (float)pr;
  }
  measure_out(st, a, s, t, s2v, out, C);
}

// ---------- prep: trig tables + deferred scale + tg/rep table ----------
__global__ void prep_kernel(const float* __restrict__ inp,
                            const float* __restrict__ theta,
                            float* __restrict__ ws, float4* __restrict__ tbl,
                            float4* __restrict__ albe, int nAlbe, SimConsts C) {
  const int i = blockIdx.x * 256 + threadIdx.x;
  float2* tt = (float2*)ws;
  float2* tq = (float2*)(ws + 256);
  if (i < DEPTH * NQ) {
    float ss, cc; sincosf(0.5f * theta[i], &ss, &cc);
    tt[i] = make_float2(cc, ss);
    float ca = (fabsf(cc) < 1e-20f) ? copysignf(1e-20f, cc) : cc;
    tq[i] = make_float2(ss / ca, ca);
  }
  if (i == 0) {
    double pr = 1.0;
    for (int j = NQ; j < DEPTH * NQ; ++j) {
      double cc = cos(0.5 * (double)theta[j]);
      pr *= cc * cc;
    }
    ws[512] = (float)pr;
  }
  if (tbl != nullptr && i < NPASS * 1024) {
    const int p = i >> 10, t = i & 1023;
    const PassK& P = C.pass[p];
    const int d = (p >> 1) + 1;
    float tg[7];
    #pragma unroll
    for (int k = 0; k < 7; ++k) {
      float ss, cc; sincosf(0.5f * theta[d * NQ + P.widx[k]], &ss, &cc);
      float ca = (fabsf(cc) < 1e-20f) ? copysignf(1e-20f, cc) : cc;
      float tv = ss / ca;
      int sg = __popc((unsigned)P.sm[k] & (unsigned)t) & 1;
      tg[k] = (k < 4) ? (sg ? -tv : tv) : (sg ? tv : -tv);
    }
    unsigned rep = 0;
    #pragma unroll
    for (int b = 0; b < 10; ++b)
      rep ^= ((t >> b) & 1u) ? (unsigned)P.pcol[b] : 0u;
    tbl[(size_t)i * 2]     = make_float4(tg[0], tg[1], tg[2], tg[3]);
    tbl[(size_t)i * 2 + 1] = make_float4(tg[4], tg[5], tg[6],
                                         __uint_as_float(rep));
  }
  if (albe != nullptr && i < nAlbe) {
    const int w = i % NQ;
    float sx, cx; sincosf(0.5f * inp[i], &sx, &cx);
    float stt, ctt; sincosf(0.5f * theta[w], &stt, &ctt);
    albe[i] = make_float4(ctt * cx, stt * sx, stt * cx, -ctt * sx);
  }
}

// ---------- host: GF(2) linear algebra for the CNOT-ring permutation ----------
static inline unsigned ffwd(unsigned x) {
  unsigned t = x;
  t ^= t >> 1; t ^= t >> 2; t ^= t >> 4; t ^= t >> 8;
  unsigned y = t & 0x1FFFu;
  y |= (((t >> 13) ^ t) & 1u) << 13;
  return y;
}
static inline unsigned finv(unsigned y) {
  unsigned x = 0;
  for (int j = 0; j <= 11; ++j) x |= (((y >> j) ^ (y >> (j + 1))) & 1u) << j;
  x |= (((y >> 12) ^ (y >> 13) ^ y) & 1u) << 12;
  x |= (((y >> 13) ^ y) & 1u) << 13;
  return x;
}
static inline int rank3n(unsigned a, unsigned b, unsigned c) {
  unsigned bas[4] = {0, 0, 0, 0};
  unsigned vv[3] = {a & 15u, b & 15u, c & 15u};
  int r = 0;
  for (int i = 0; i < 3; ++i) {
    unsigned u = vv[i];
    for (int bit = 3; bit >= 0; --bit)
      if (((u >> bit) & 1u) && bas[bit]) u ^= bas[bit];
    if (u) { bas[31 - __builtin_clz(u)] = u; ++r; }
  }
  return r;
}
static inline unsigned phi_full(unsigned m, const unsigned* ac) {
  unsigned d = 0;
  for (int j = 0; j < 8; ++j)
    if ((m >> (6 + j)) & 1u) d ^= ac[j];
  return m ^ d;
}
static inline int par(unsigned x) { return __builtin_popcount(x) & 1; }

static int scoreA(const unsigned* ac, const u16 am[14][7], int bail) {
  int s = 0;
  for (int p = 0; p < 14; ++p) {
    unsigned pm[7];
    for (int i = 0; i < 7; ++i) pm[i] = phi_full((unsigned)am[p][i], ac) & 15u;
    int best = 0;
    for (int x = 0; x < 7 && best < 3; ++x)
      for (int y = x + 1; y < 7 && best < 3; ++y)
        for (int z = y + 1; z < 7 && best < 3; ++z) {
          int r = rank3n(pm[x], pm[y], pm[z]);
          if (r > best) best = r;
        }
    if (best < 3) s += 3 - best;
    if (s >= bail) return s;
  }
  return s;
}

extern "C" void kernel_launch(void* const* d_in, const int* in_sizes, int n_in,
                              void* d_out, int out_size, void* d_ws, size_t ws_size,
                              hipStream_t stream) {
  const float* inp = (const float*)d_in[0];
  const float* theta = (const float*)d_in[1];
  float* out = (float*)d_out;
  const int batch = in_sizes[0] / NQ;

  // ---- collect per-pass wire masks (K cols) and sign rows (L rows)
  u16 Lc[NQ], Kc[NQ];
  u16 allmask[14][7]; unsigned allrow[14][7];
  u16 zrow[NQ];
  for (int j = 0; j < NQ; ++j) { Lc[j] = (u16)(1u << j); Kc[j] = (u16)(1u << j); }
  for (int d = 1; d <= 8; ++d) {
    u16 nL[NQ], nK[NQ];
    for (int j = 0; j < NQ; ++j) nL[j] = (u16)ffwd((unsigned)Lc[j]);
    for (int j = 0; j < NQ; ++j) {
      unsigned fj = finv(1u << j);
      unsigned v = 0;
      for (int b = 0; b < NQ; ++b) if ((fj >> b) & 1u) v ^= Kc[b];
      nK[j] = (u16)v;
    }
    for (int j = 0; j < NQ; ++j) { Lc[j] = nL[j]; Kc[j] = nK[j]; }

    if (d <= 7) {
      for (int pg = 0; pg < 2; ++pg) {
        const int p = (d - 1) * 2 + pg;
        const int wbase = pg * 7;
        for (int i = 0; i < 7; ++i) {
          const int bit = 13 - (wbase + i);
          allmask[p][i] = Kc[bit];
          unsigned r = 0;
          for (int j = 0; j < NQ; ++j) r |= ((unsigned)(Lc[j] >> bit) & 1u) << j;
          allrow[p][i] = r;
        }
      }
    } else {
      for (int w = 0; w < NQ; ++w) {
        const int bit = 13 - w;
        unsigned r = 0;
        for (int j = 0; j < NQ; ++j) r |= ((unsigned)(Lc[j] >> bit) & 1u) << j;
        zrow[w] = (u16)r;
      }
    }
  }

  // ---- search layout map A (8 cols -> low4) so every pass has a rank-3 triple
  unsigned acol[8] = {0, 0, 0, 0, 0, 0, 0, 0};
  int bestSc = scoreA(acol, allmask, 1 << 30);
  if (bestSc > 0) {
    unsigned long long seed = 88172645463325252ULL;
    for (int it = 0; it < 20000 && bestSc > 0; ++it) {
      unsigned cand[8];
      for (int j = 0; j < 8; ++j) {
        seed ^= seed << 13; seed ^= seed >> 7; seed ^= seed << 17;
        cand[j] = (unsigned)(seed & 15u);
      }
      int sc = scoreA(cand, allmask, bestSc);
      if (sc < bestSc) {
        bestSc = sc;
        for (int j = 0; j < 8; ++j) acol[j] = cand[j];
      }
    }
  }

  // ---- build pass constants
  SimConsts C;
  u16 mkLast[4] = {0, 0, 0, 0};
  unsigned lcolLast[10] = {0};
  for (int p = 0; p < 14; ++p) {
    PassK& P = C.pass[p];
    const int pg = p & 1, wbase = pg * 7;

    unsigned pm[7];
    for (int i = 0; i < 7; ++i) pm[i] = phi_full((unsigned)allmask[p][i], acol) & 15u;
    int ca = 0, cb = 1, cc2 = 2, best = -1;
    for (int x = 0; x < 7; ++x)
      for (int y = x + 1; y < 7; ++y)
        for (int z = y + 1; z < 7; ++z) {
          int r = rank3n(pm[x], pm[y], pm[z]);
          if (r > best) { best = r; ca = x; cb = y; cc2 = z; }
        }

    unsigned cmL[3] = {allmask[p][ca], allmask[p][cb], allmask[p][cc2]};
    unsigned srowAll[7];
    srowAll[4] = allrow[p][ca]; srowAll[5] = allrow[p][cb]; srowAll[6] = allrow[p][cc2];
    P.widx[4] = (u16)(wbase + ca); P.widx[5] = (u16)(wbase + cb);
    P.widx[6] = (u16)(wbase + cc2);
    u16 mk[4]; int ii = 0;
    for (int i = 0; i < 7; ++i)
      if (i != ca && i != cb && i != cc2) {
        mk[ii] = allmask[p][i]; srowAll[ii] = allrow[p][i];
        P.widx[ii] = (u16)(wbase + i); ++ii;
      }
    if (p == 13) for (int i = 0; i < 4; ++i) mkLast[i] = mk[i];

    unsigned red[14] = {0};
    auto tryAdd = [&](unsigned x) -> bool {
      while (x) {
        int h = 31 - __builtin_clz(x);
        if (!red[h]) { red[h] = x; return true; }
        x ^= red[h];
      }
      return false;
    };
    for (int i = 0; i < 7; ++i) tryAdd((unsigned)allmask[p][i]);

    unsigned nb[4] = {0, 0, 0, 0};
    for (int i = 0; i < 3; ++i) {
      unsigned u = pm[i == 0 ? ca : (i == 1 ? cb : cc2)];
      for (int bit = 3; bit >= 0; --bit)
        if (((u >> bit) & 1u) && nb[bit]) u ^= nb[bit];
      if (u) nb[31 - __builtin_clz(u)] = u;
    }
    unsigned uTarget = 0;
    for (unsigned v = 1; v < 16; ++v) {
      unsigned r = v;
      for (int bit = 3; bit >= 0; --bit)
        if (((r >> bit) & 1u) && nb[bit]) r ^= nb[bit];
      if (r) { uTarget = v; break; }
    }
    unsigned scol[7];
    {
      bool ok = false;
      for (unsigned h = 0; h < 256u && !ok; ++h) {
        unsigned d4 = 0;
        for (int j = 0; j < 8; ++j) if ((h >> j) & 1u) d4 ^= acol[j];
        unsigned v = ((uTarget ^ d4) & 15u) | (h << 6);
        if (v && tryAdd(v)) { scol[0] = v; ok = true; }
      }
      for (unsigned cand = 1; cand < 16384u && !ok; ++cand)
        if (tryAdd(cand)) { scol[0] = cand; ok = true; }
    }
    for (int i2 = 1; i2 < 7; ++i2) {
      bool ok = false;
      for (unsigned h = 1; h < 256u && !ok; ++h)
        if (tryAdd(h << 6)) { scol[i2] = h << 6; ok = true; }
      for (unsigned cand = 1; cand < 16384u && !ok; ++cand)
        if (tryAdd(cand)) { scol[i2] = cand; ok = true; }
    }

    unsigned lcol[10] = {cmL[0], cmL[1], scol[0], cmL[2],
                         scol[1], scol[2], scol[3], scol[4], scol[5], scol[6]};
    for (int b = 0; b < 10; ++b) P.pcol[b] = (u16)phi_full(lcol[b], acol);
    if (p == 13) for (int b = 0; b < 10; ++b) lcolLast[b] = lcol[b];

    for (int i = 0; i < 7; ++i) {
      unsigned m = 0;
      for (int b = 0; b < 10; ++b)
        m |= (unsigned)par(srowAll[i] & lcol[b]) << b;
      P.sm[i] = (u16)m;
    }
    for (int e = 0; e < 16; ++e) {
      unsigned v = 0;
      for (int i = 0; i < 4; ++i)
        if ((e >> i) & 1) v ^= (unsigned)mk[i];
      P.pxm[e] = (u16)phi_full(v, acol);
    }
  }

  for (int w = 0; w < NQ; ++w) {
    unsigned zf = 0;
    for (int i = 0; i < 4; ++i)
      zf |= (unsigned)par((unsigned)zrow[w] & (unsigned)mkLast[i]) << i;
    C.zfreq[w] = (u16)zf;
    unsigned m = 0;
    for (int b = 0; b < 10; ++b)
      m |= (unsigned)par((unsigned)zrow[w] & lcolLast[b]) << b;
    C.zm[w] = (u16)m;
  }
  for (int e = 0; e < 16; ++e) {
    unsigned d4 = 0;
    for (int k = 0; k < 4; ++k)
      if ((e >> k) & 1) d4 ^= acol[4 + k];
    C.de[e] = (u16)d4;
  }
  for (int j = 0; j < 4; ++j) C.dcolw[j] = (u16)acol[j];

  // ---- workspace layout ----
  const size_t needT = 4096;
  const size_t tblOff = 8192;
  const size_t tblBytes = (size_t)NPASS * 1024 * 32;
  const size_t needTbl = tblOff + tblBytes;           // 466944
  const bool useT = ws_size >= needT;
  const bool useTbl = ws_size >= needTbl;
  const size_t albeOff = useTbl ? needTbl : 4096;
  const size_t needA = albeOff + (size_t)batch * NQ * sizeof(float4);
  const bool useA = useT && ws_size >= needA;

  float* wsf = (float*)d_ws;
  float2* tt = (float2*)wsf;
  float2* tq = (float2*)(wsf + 256);
  float* s2p = wsf + 512;
  float4* tbl = (float4*)((char*)d_ws + tblOff);
  float4* albe = (float4*)((char*)d_ws + albeOff);

  if (useT) {
    const int nAlbe = useA ? batch * NQ : 0;
    int nwork = DEPTH * NQ;
    if (useTbl && NPASS * 1024 > nwork) nwork = NPASS * 1024;
    if (useA && nAlbe > nwork) nwork = nAlbe;
    prep_kernel<<<(nwork + 255) / 256, 256, 0, stream>>>(
        inp, theta, wsf, useTbl ? tbl : nullptr, useA ? albe : nullptr,
        nAlbe, C);
    if (useTbl) {
      qsim_tbl_kernel<<<batch, TPB, 0, stream>>>(inp, theta, out, tt, s2p,
                                                 albe, useA ? 1 : 0, tbl, C);
    } else {
      qsim_kernel<true><<<batch, TPB, 0, stream>>>(inp, theta, out, tt, tq,
                                                   s2p, albe, useA ? 1 : 0, C);
    }
  } else {
    qsim_kernel<false><<<batch, TPB, 0, stream>>>(inp, theta, out, nullptr,
                                                  nullptr, nullptr, nullptr, 0, C);
  }
}